// Round 19
// baseline (1066.709 us; speedup 1.0000x reference)
//
#include <hip/hip_runtime.h>
#include <math.h>

// R18 = R17 with NS=1 (R16's per-seq flow) + register-FF kept => per-wave
// slot = HB (2432B) only. 512 blocks x 1024 thr (half-cell, 128 seqs):
// LDS = 12288 g2 + 16x2432 HB + 4352 peL = 55552B -> TWO blocks fit per CU
// (111KB < 160KB) -> target 32 waves/CU (8/SIMD), 2x all prior occupancy.
// Conv: e-dim split across thread pairs (512 ch/block, no duplicate FLOPs),
// partials combined via LDS.

typedef __attribute__((ext_vector_type(8))) short s8v;
typedef __attribute__((ext_vector_type(4))) short s4v;
typedef __attribute__((ext_vector_type(4))) float f4v;
typedef __attribute__((ext_vector_type(4))) unsigned int u4v;

#define MFMA32(A, B, C) __builtin_amdgcn_mfma_f32_16x16x32_bf16((A), (B), (C), 0, 0, 0)
#define MFMA16(A, B, C) __builtin_amdgcn_mfma_f32_16x16x16bf16_1k((A), (B), (C), 0, 0, 0)

static __device__ __forceinline__ unsigned short f2b(float f) {
  return __builtin_bit_cast(unsigned short, (__bf16)f);
}
static __device__ __forceinline__ float b2f(unsigned short h) {
  return __builtin_bit_cast(float, ((unsigned)h) << 16);
}
static __device__ __forceinline__ s4v c4(f4v v) {
  s4v r;
  r[0] = (short)f2b(v[0]); r[1] = (short)f2b(v[1]);
  r[2] = (short)f2b(v[2]); r[3] = (short)f2b(v[3]);
  return r;
}

// ---- ws layout (bytes) ----
// [0)       B-pack 1KB tiles T=0..191 (qkv V-op B, ow B, ff unused regions)
// [196608)  A-pack 1KB tiles T=192..223 (Wq/Wk A-op)
// [229376)  WO16 512B tiles E=0..31  (Wo^T MFMA16 B-op)
// [245760)  W1A 1KB tiles T2=0..63  (ff1 A-op: T2 = l*32 + ft*2 + kk)
// [311296)  W2T 512B tiles E2=0..127 (ff2^T MFMA16 B-op: E2 = l*64 + ft*4 + jo)
__global__ __launch_bounds__(256) void wpack(
    const float* __restrict__ qkv_w, const float* __restrict__ ow,
    const float* __restrict__ ff1_w, const float* __restrict__ ff2_w,
    unsigned int* __restrict__ ws) {
  int gid = blockIdx.x * 256 + threadIdx.x;   // 112 blocks -> tIdx 0..447
  int tIdx = gid >> 6, lane = gid & 63;
  int ln = lane & 15, grp = lane >> 4;
  if (tIdx < 224) {
    const float* src;
    if (tIdx < 48) {
      int l = tIdx / 24, r = tIdx % 24, kk = r / 12, j = r % 12;
      src = qkv_w + l * 12288 + (j * 16 + ln) * 64 + kk * 32 + grp * 8;
    } else if (tIdx < 64) {
      int u = tIdx - 48, l = u / 8, r = u % 8, kk = r / 4, j = r % 4;
      src = ow + l * 4096 + (j * 16 + ln) * 64 + kk * 32 + grp * 8;
    } else if (tIdx < 128) {
      int u = tIdx - 64, l = u / 32, r = u % 32, kk = r / 16, j = r % 16;
      src = ff1_w + l * 16384 + (j * 16 + ln) * 64 + kk * 32 + grp * 8;
    } else if (tIdx < 192) {
      int u = tIdx - 128, l = u / 32, r = u % 32, kk = r / 4, j = r % 4;
      src = ff2_w + l * 16384 + (j * 16 + ln) * 256 + kk * 32 + grp * 8;
    } else {
      int u = tIdx - 192, l = u / 16, r = u % 16, mat = r / 8, q = r % 8, jo = q / 2, kk = q % 2;
      src = qkv_w + l * 12288 + mat * 4096 + (jo * 16 + ln) * 64 + kk * 32 + grp * 8;
    }
    unsigned p[4];
#pragma unroll
    for (int e = 0; e < 4; ++e)
      p[e] = (unsigned)f2b(src[2 * e]) | ((unsigned)f2b(src[2 * e + 1]) << 16);
    u4v val = {p[0], p[1], p[2], p[3]};
    *(u4v*)(ws + (size_t)gid * 4) = val;
  } else if (tIdx < 256) {
    int E = tIdx - 224, l = E / 16, r = E % 16, hh = r / 4, jo = r % 4;
    const float* src = ow + l * 4096 + (jo * 16 + ln) * 64 + hh * 16 + grp * 4;
    unsigned lo = (unsigned)f2b(src[0]) | ((unsigned)f2b(src[1]) << 16);
    unsigned hi = (unsigned)f2b(src[2]) | ((unsigned)f2b(src[3]) << 16);
    *(uint2*)((char*)ws + 229376 + E * 512 + lane * 8) = make_uint2(lo, hi);
  } else if (tIdx < 320) {
    int u2 = tIdx - 256, l = u2 / 32, r = u2 % 32, ft = r / 2, kk = r % 2;
    const float* src = ff1_w + l * 16384 + (ft * 16 + ln) * 64 + kk * 32 + grp * 8;
    unsigned p[4];
#pragma unroll
    for (int e = 0; e < 4; ++e)
      p[e] = (unsigned)f2b(src[2 * e]) | ((unsigned)f2b(src[2 * e + 1]) << 16);
    *(u4v*)((char*)ws + 245760 + u2 * 1024 + lane * 16) = (u4v){p[0], p[1], p[2], p[3]};
  } else if (tIdx < 448) {
    int E = tIdx - 320, l = E / 64, r = E % 64, ft = r / 4, jo = r % 4;
    const float* src = ff2_w + l * 16384 + (jo * 16 + ln) * 256 + ft * 16 + grp * 4;
    unsigned lo = (unsigned)f2b(src[0]) | ((unsigned)f2b(src[1]) << 16);
    unsigned hi = (unsigned)f2b(src[2]) | ((unsigned)f2b(src[3]) << 16);
    *(uint2*)((char*)ws + 311296 + E * 512 + lane * 8) = make_uint2(lo, hi);
  }
}

__global__ __launch_bounds__(1024) void prithvi_fused(
    const float* __restrict__ x,     const float* __restrict__ conv_w,
    const float* __restrict__ bn_g,  const float* __restrict__ bn_b,
    const float* __restrict__ bn_m,  const float* __restrict__ bn_v,
    const float* __restrict__ w_in,  const float* __restrict__ qkv_b,
    const float* __restrict__ ob,    const float* __restrict__ ln1_g,
    const float* __restrict__ ln1_b, const float* __restrict__ ff1_b,
    const float* __restrict__ ff2_b, const float* __restrict__ ln2_g,
    const float* __restrict__ ln2_b, const float* __restrict__ w_out,
    const float* __restrict__ b_out, const float* __restrict__ ws,
    float* __restrict__ out)
{
  // g2 12288 | HB slots 16x2432=38912 (conv stg 12288 + pscr 24576 alias) | peL 4352
  __shared__ __align__(16) char smem[55552];
  unsigned short* g2 = (unsigned short*)smem;   // [128 sl][12 t][4 c] bf16
  char* twb = smem + 12288;
  float* peL = (float*)(smem + 51200);           // [16 t][stride 68] fp32

  const int blk = blockIdx.x, sp = blk >> 1, bh = blk & 1;
  const int tid = threadIdx.x, lane = tid & 63, wave = tid >> 6;

  // ---- pe table ----
  {
    int t_ = tid >> 6, d_ = tid & 63;
    float freq = expf(-(float)(d_ & ~1) * (9.210340371976184f / 64.f));
    float a = freq * (float)t_;
    peL[t_ * 68 + d_] = (d_ & 1) ? cosf(a) : sinf(a);
  }

  // ---- conv: 512 channels (this half's 128 subpixels x 4 c), e split in half
  //      per thread pair; partials combined via LDS ----
  {
    float* stg  = (float*)twb;            // 12288B: e-block staging
    float* pscr = (float*)(twb + 12288);  // 24576B: eh=1 partials
    float acc[12];
#pragma unroll
    for (int t = 0; t < 12; ++t) acc[t] = 0.f;
    const int jj = tid & 127;             // subpixel within half-cell
    const int c2 = tid >> 7;              // 0..7
    const int c_ = c2 & 3, eh = c2 >> 2;  // channel group, e-half
    const int oc = c_ * 256 + bh * 128 + jj;
    const float* wrow = conv_w + (size_t)oc * 1024;
#pragma unroll 1
    for (int p = 0; p < 4; ++p) {
      for (int ch2 = tid; ch2 < 3072; ch2 += 1024) {
        int e = ch2 / 12, t = ch2 - 12 * e;
        stg[t * 256 + e] = x[(size_t)((p * 256 + e) * 12 + t) * 256 + sp];
      }
      __syncthreads();
      if ((p >> 1) == eh) {
        for (int eb = 0; eb < 256; eb += 4) {
          float4 w4 = *(const float4*)(wrow + p * 256 + eb);
#pragma unroll
          for (int t = 0; t < 12; ++t) {
            float4 xv = *(const float4*)&stg[t * 256 + eb];
            acc[t] = fmaf(xv.x, w4.x, acc[t]);
            acc[t] = fmaf(xv.y, w4.y, acc[t]);
            acc[t] = fmaf(xv.z, w4.z, acc[t]);
            acc[t] = fmaf(xv.w, w4.w, acc[t]);
          }
        }
      }
      __syncthreads();
    }
    if (eh == 1) {
#pragma unroll
      for (int t = 0; t < 12; ++t) pscr[(c_ * 128 + jj) * 12 + t] = acc[t];
    }
    __syncthreads();
    if (eh == 0) {
      float sc = bn_g[oc] * rsqrtf(bn_v[oc] + 1e-5f);
      float sh = fmaf(-bn_m[oc], sc, bn_b[oc]);
#pragma unroll
      for (int t = 0; t < 12; ++t) {
        float z = fmaf(acc[t] + pscr[(c_ * 128 + jj) * 12 + t], sc, sh);
        g2[jj * 48 + t * 4 + c_] = f2b(0.5f * z * (1.f + erff(z * 0.70710678118654752f)));
      }
    }
  }
  __syncthreads();   // g2 + peL read-only; twb free for HB slots

  // ---------------- phase 3: 1 seq at a time, 16 waves, 8 seqs/wave ----
  const int ln = lane & 15, grp = lane >> 4;
  char* HB = twb + wave * 2432;
  const u4v* WS = (const u4v*)ws;
#define BT(T) __builtin_bit_cast(s8v, WS[(T) * 64 + lane])
#define BT2(T2) BT(240 + (T2))
#define WO16(E) __builtin_bit_cast(s4v, *(const uint2*)((const char*)ws + 229376 + (E) * 512 + lane * 8))
#define W2T(E2) WO16(160 + (E2))
#define STROW(BUF, ROW, COL, VAL) \
  ((unsigned short*)(BUF))[(ROW) * 76 + (COL)] = (VAL)

  const float bo0 = b_out[0];

#pragma unroll 1
  for (int itr = 0; itr < 8; ++itr) {
    const int sl = wave * 8 + itr;   // local seq 0..127
    f4v v[4];

    // ---- h0 (fp32 C-frag) -> HB bf16 ----
    {
      int tb = (grp < 3) ? grp * 4 : 0;
#pragma unroll
      for (int i = 0; i < 4; ++i) {
        uint2 gu = *(const uint2*)(g2 + sl * 48 + (tb + i) * 4);
        float g0 = b2f((unsigned short)(gu.x & 0xffff));
        float g1 = b2f((unsigned short)(gu.x >> 16));
        float g2v = b2f((unsigned short)(gu.y & 0xffff));
        float g3 = b2f((unsigned short)(gu.y >> 16));
#pragma unroll
        for (int j = 0; j < 4; ++j) {
          float4 wi = *(const float4*)(w_in + (j * 16 + ln) * 4);
          float peij = peL[(grp * 4 + i) * 68 + j * 16 + ln];
          v[j][i] = fmaf(g0, wi.x, fmaf(g1, wi.y,
                    fmaf(g2v, wi.z, fmaf(g3, wi.w, peij))));
        }
      }
#pragma unroll
      for (int i = 0; i < 4; ++i)
#pragma unroll
        for (int j = 0; j < 4; ++j)
          STROW(HB, grp * 4 + i, j * 16 + ln, f2b(v[j][i]));
    }

#pragma unroll 1
    for (int l = 0; l < 2; ++l) {
      const f4v z4 = {0.f, 0.f, 0.f, 0.f};
      s4v Ot[4];
      // ---- fused per-head QKV + attention, all registers ----
      {
        s8v a0 = *(const s8v*)(HB + ln * 152 + grp * 16);
        s8v a1 = *(const s8v*)(HB + ln * 152 + 64 + grp * 16);
#pragma unroll
        for (int hh = 0; hh < 4; ++hh) {
          float4 bq = *(const float4*)(qkv_b + l * 192 + hh * 16 + grp * 4);
          f4v cq = {bq.x, bq.y, bq.z, bq.w};
          cq = MFMA32(BT(192 + l * 16 + hh * 2 + 0), a0, cq);
          cq = MFMA32(BT(192 + l * 16 + hh * 2 + 1), a1, cq);
          float4 bk = *(const float4*)(qkv_b + l * 192 + 64 + hh * 16 + grp * 4);
          f4v ck = {bk.x, bk.y, bk.z, bk.w};
          ck = MFMA32(BT(192 + l * 16 + 8 + hh * 2 + 0), a0, ck);
          ck = MFMA32(BT(192 + l * 16 + 8 + hh * 2 + 1), a1, ck);
          float bb = qkv_b[l * 192 + 128 + hh * 16 + ln];
          f4v cv = {bb, bb, bb, bb};
          cv = MFMA32(a0, BT(l * 24 + 8 + hh), cv);
          cv = MFMA32(a1, BT(l * 24 + 20 + hh), cv);
          s4v q4 = c4(cq), k4 = c4(ck), v4 = c4(cv);
          f4v sc = MFMA16(k4, q4, z4);   // lane: score(q=ln, k=grp*4+i)
          float e0, e1, e2, e3;
          if (grp == 3) { e0 = e1 = e2 = e3 = 0.f; }
          else {
            e0 = __expf(sc[0] * 0.25f); e1 = __expf(sc[1] * 0.25f);
            e2 = __expf(sc[2] * 0.25f); e3 = __expf(sc[3] * 0.25f);
          }
          float sm = (e0 + e1) + (e2 + e3);
          sm += __shfl_xor(sm, 16);
          sm += __shfl_xor(sm, 32);
          float inv = __builtin_amdgcn_rcpf(sm);
          s4v aP;
          aP[0] = (short)f2b(e0 * inv); aP[1] = (short)f2b(e1 * inv);
          aP[2] = (short)f2b(e2 * inv); aP[3] = (short)f2b(e3 * inv);
          Ot[hh] = c4(MFMA16(v4, aP, z4));
        }
      }
      // ---- O-proj ----
      {
#pragma unroll
        for (int jo = 0; jo < 4; ++jo) {
          float bb = ob[l * 64 + jo * 16 + ln];
          f4v bb4 = {bb, bb, bb, bb};
          v[jo] += bb4;
        }
#pragma unroll
        for (int hh = 0; hh < 4; ++hh)
#pragma unroll
          for (int jo = 0; jo < 4; ++jo)
            v[jo] = MFMA16(Ot[hh], WO16(l * 16 + hh * 4 + jo), v[jo]);
      }
      // ---- LN1 -> HB ----
      {
        const float* gp = ln1_g + l * 64;
        const float* bp = ln1_b + l * 64;
#pragma unroll
        for (int i = 0; i < 4; ++i) {
          float sm = v[0][i] + v[1][i] + v[2][i] + v[3][i];
          sm += __shfl_xor(sm, 1); sm += __shfl_xor(sm, 2);
          sm += __shfl_xor(sm, 4); sm += __shfl_xor(sm, 8);
          float mean = sm * 0.015625f;
          float q = 0.f;
#pragma unroll
          for (int j = 0; j < 4; ++j) { float d = v[j][i] - mean; q = fmaf(d, d, q); }
          q += __shfl_xor(q, 1); q += __shfl_xor(q, 2);
          q += __shfl_xor(q, 4); q += __shfl_xor(q, 8);
          float rs = rsqrtf(q * 0.015625f + 1e-5f);
#pragma unroll
          for (int j = 0; j < 4; ++j) {
            float nv = fmaf((v[j][i] - mean) * rs, gp[j * 16 + ln], bp[j * 16 + ln]);
            v[j][i] = nv;
            STROW(HB, grp * 4 + i, j * 16 + ln, f2b(nv));
          }
        }
      }
      // ---- FF: register-resident (F^T tiles; F^T-frag-as-A == F) ----
      {
        s8v ha0 = *(const s8v*)(HB + ln * 152 + grp * 16);
        s8v ha1 = *(const s8v*)(HB + ln * 152 + 64 + grp * 16);
#pragma unroll
        for (int jo = 0; jo < 4; ++jo) {
          float bb = ff2_b[l * 64 + jo * 16 + ln];
          f4v bb4 = {bb, bb, bb, bb};
          v[jo] += bb4;
        }
#pragma unroll
        for (int ft = 0; ft < 16; ++ft) {
          float4 b4 = *(const float4*)(ff1_b + l * 256 + ft * 16 + grp * 4);
          f4v c = {b4.x, b4.y, b4.z, b4.w};
          c = MFMA32(BT2(l * 32 + ft * 2 + 0), ha0, c);
          c = MFMA32(BT2(l * 32 + ft * 2 + 1), ha1, c);
#pragma unroll
          for (int i = 0; i < 4; ++i) c[i] = fmaxf(c[i], 0.f);
          s4v fv = c4(c);
          v[0] = MFMA16(fv, W2T(l * 64 + ft * 4 + 0), v[0]);
          v[1] = MFMA16(fv, W2T(l * 64 + ft * 4 + 1), v[1]);
          v[2] = MFMA16(fv, W2T(l * 64 + ft * 4 + 2), v[2]);
          v[3] = MFMA16(fv, W2T(l * 64 + ft * 4 + 3), v[3]);
        }
      }
      // ---- LN2 (store HB only if another layer follows) ----
      {
        const float* gp = ln2_g + l * 64;
        const float* bp = ln2_b + l * 64;
#pragma unroll
        for (int i = 0; i < 4; ++i) {
          float sm = v[0][i] + v[1][i] + v[2][i] + v[3][i];
          sm += __shfl_xor(sm, 1); sm += __shfl_xor(sm, 2);
          sm += __shfl_xor(sm, 4); sm += __shfl_xor(sm, 8);
          float mean = sm * 0.015625f;
          float q = 0.f;
#pragma unroll
          for (int j = 0; j < 4; ++j) { float d = v[j][i] - mean; q = fmaf(d, d, q); }
          q += __shfl_xor(q, 1); q += __shfl_xor(q, 2);
          q += __shfl_xor(q, 4); q += __shfl_xor(q, 8);
          float rs = rsqrtf(q * 0.015625f + 1e-5f);
#pragma unroll
          for (int j = 0; j < 4; ++j) {
            float nv = fmaf((v[j][i] - mean) * rs, gp[j * 16 + ln], bp[j * 16 + ln]);
            v[j][i] = nv;
            if (l == 0) STROW(HB, grp * 4 + i, j * 16 + ln, f2b(nv));
          }
        }
      }
    } // layer

    // ---- head ----
    {
      float dp = 0.f;
#pragma unroll
      for (int j = 0; j < 4; ++j) {
        float c0 = (grp < 3) ? (v[j][0] + v[j][1] + v[j][2] + v[j][3]) : 0.f;
        c0 += __shfl_xor(c0, 16);
        c0 += __shfl_xor(c0, 32);
        dp = fmaf(c0, w_out[j * 16 + ln], dp);
      }
      dp += __shfl_xor(dp, 1);
      dp += __shfl_xor(dp, 2);
      dp += __shfl_xor(dp, 4);
      dp += __shfl_xor(dp, 8);
      if (lane == 0) {
        const int s = bh * 128 + sl;
        float logit = dp * (1.f / 12.f) + bo0;
        int hf = ((sp >> 4) << 4) | (s >> 4);
        int wf = ((sp & 15) << 4) | (s & 15);
        out[hf * 256 + wf] = 1.f / (1.f + expf(-logit));
      }
    }
  } // seq loop
#undef BT
#undef BT2
#undef WO16
#undef W2T
#undef STROW
}

extern "C" void kernel_launch(void* const* d_in, const int* in_sizes, int n_in,
                              void* d_out, int out_size, void* d_ws, size_t ws_size,
                              hipStream_t stream) {
  (void)in_sizes; (void)n_in; (void)out_size; (void)ws_size;
  wpack<<<112, 256, 0, stream>>>(
      (const float*)d_in[7],  (const float*)d_in[9],
      (const float*)d_in[13], (const float*)d_in[15], (unsigned int*)d_ws);
  prithvi_fused<<<512, 1024, 0, stream>>>(
      (const float*)d_in[0],  (const float*)d_in[1],  (const float*)d_in[2],
      (const float*)d_in[3],  (const float*)d_in[4],  (const float*)d_in[5],
      (const float*)d_in[6],  (const float*)d_in[8],  (const float*)d_in[10],
      (const float*)d_in[11], (const float*)d_in[12], (const float*)d_in[14],
      (const float*)d_in[16], (const float*)d_in[17], (const float*)d_in[18],
      (const float*)d_in[19], (const float*)d_in[20], (const float*)d_ws,
      (float*)d_out);
}

// Round 20
// 906.596 us; speedup vs baseline: 1.1766x; 1.1766x over previous
//
#include <hip/hip_runtime.h>
#include <math.h>

// R19 = R16 (749us best: 256 blocks x 1024 thr, NS=1) + register-resident FF
// from R18 (isolated A/B vs R16's LDS-FF; R18's 512-block test was grid-
// confounded). Per-wave slot = HB only; FF1 = mfma32(A=W1A, B=h-frag),
// ReLU in-reg, F^T-frag-as-A feeds FF2 as mfma16 with W2T packs.
// Occupancy ceiling confirmed: 1 block/CU always; 16 waves/CU is max.

typedef __attribute__((ext_vector_type(8))) short s8v;
typedef __attribute__((ext_vector_type(4))) short s4v;
typedef __attribute__((ext_vector_type(4))) float f4v;
typedef __attribute__((ext_vector_type(4))) unsigned int u4v;

#define MFMA32(A, B, C) __builtin_amdgcn_mfma_f32_16x16x32_bf16((A), (B), (C), 0, 0, 0)
#define MFMA16(A, B, C) __builtin_amdgcn_mfma_f32_16x16x16bf16_1k((A), (B), (C), 0, 0, 0)

static __device__ __forceinline__ unsigned short f2b(float f) {
  return __builtin_bit_cast(unsigned short, (__bf16)f);
}
static __device__ __forceinline__ float b2f(unsigned short h) {
  return __builtin_bit_cast(float, ((unsigned)h) << 16);
}
static __device__ __forceinline__ s4v c4(f4v v) {
  s4v r;
  r[0] = (short)f2b(v[0]); r[1] = (short)f2b(v[1]);
  r[2] = (short)f2b(v[2]); r[3] = (short)f2b(v[3]);
  return r;
}

// ---- ws layout (bytes) ----
// [0)       B-pack 1KB tiles T=0..191 (qkv V B-op, ow B; ff regions unused)
// [196608)  A-pack 1KB tiles T=192..223 (Wq/Wk A-op)
// [229376)  WO16 512B tiles E=0..31  (Wo^T MFMA16 B-op)
// [245760)  W1A 1KB tiles T2=0..63  (ff1 A-op: T2 = l*32 + ft*2 + kk)
// [311296)  W2T 512B tiles E2=0..127 (ff2^T MFMA16 B-op: E2 = l*64 + ft*4 + jo)
__global__ __launch_bounds__(256) void wpack(
    const float* __restrict__ qkv_w, const float* __restrict__ ow,
    const float* __restrict__ ff1_w, const float* __restrict__ ff2_w,
    unsigned int* __restrict__ ws) {
  int gid = blockIdx.x * 256 + threadIdx.x;   // 112 blocks -> tIdx 0..447
  int tIdx = gid >> 6, lane = gid & 63;
  int ln = lane & 15, grp = lane >> 4;
  if (tIdx < 224) {
    const float* src;
    if (tIdx < 48) {
      int l = tIdx / 24, r = tIdx % 24, kk = r / 12, j = r % 12;
      src = qkv_w + l * 12288 + (j * 16 + ln) * 64 + kk * 32 + grp * 8;
    } else if (tIdx < 64) {
      int u = tIdx - 48, l = u / 8, r = u % 8, kk = r / 4, j = r % 4;
      src = ow + l * 4096 + (j * 16 + ln) * 64 + kk * 32 + grp * 8;
    } else if (tIdx < 128) {
      int u = tIdx - 64, l = u / 32, r = u % 32, kk = r / 16, j = r % 16;
      src = ff1_w + l * 16384 + (j * 16 + ln) * 64 + kk * 32 + grp * 8;
    } else if (tIdx < 192) {
      int u = tIdx - 128, l = u / 32, r = u % 32, kk = r / 4, j = r % 4;
      src = ff2_w + l * 16384 + (j * 16 + ln) * 256 + kk * 32 + grp * 8;
    } else {
      int u = tIdx - 192, l = u / 16, r = u % 16, mat = r / 8, q = r % 8, jo = q / 2, kk = q % 2;
      src = qkv_w + l * 12288 + mat * 4096 + (jo * 16 + ln) * 64 + kk * 32 + grp * 8;
    }
    unsigned p[4];
#pragma unroll
    for (int e = 0; e < 4; ++e)
      p[e] = (unsigned)f2b(src[2 * e]) | ((unsigned)f2b(src[2 * e + 1]) << 16);
    u4v val = {p[0], p[1], p[2], p[3]};
    *(u4v*)(ws + (size_t)gid * 4) = val;
  } else if (tIdx < 256) {
    int E = tIdx - 224, l = E / 16, r = E % 16, hh = r / 4, jo = r % 4;
    const float* src = ow + l * 4096 + (jo * 16 + ln) * 64 + hh * 16 + grp * 4;
    unsigned lo = (unsigned)f2b(src[0]) | ((unsigned)f2b(src[1]) << 16);
    unsigned hi = (unsigned)f2b(src[2]) | ((unsigned)f2b(src[3]) << 16);
    *(uint2*)((char*)ws + 229376 + E * 512 + lane * 8) = make_uint2(lo, hi);
  } else if (tIdx < 320) {
    int u2 = tIdx - 256, l = u2 / 32, r = u2 % 32, ft = r / 2, kk = r % 2;
    const float* src = ff1_w + l * 16384 + (ft * 16 + ln) * 64 + kk * 32 + grp * 8;
    unsigned p[4];
#pragma unroll
    for (int e = 0; e < 4; ++e)
      p[e] = (unsigned)f2b(src[2 * e]) | ((unsigned)f2b(src[2 * e + 1]) << 16);
    *(u4v*)((char*)ws + 245760 + u2 * 1024 + lane * 16) = (u4v){p[0], p[1], p[2], p[3]};
  } else if (tIdx < 448) {
    int E = tIdx - 320, l = E / 64, r = E % 64, ft = r / 4, jo = r % 4;
    const float* src = ff2_w + l * 16384 + (jo * 16 + ln) * 256 + ft * 16 + grp * 4;
    unsigned lo = (unsigned)f2b(src[0]) | ((unsigned)f2b(src[1]) << 16);
    unsigned hi = (unsigned)f2b(src[2]) | ((unsigned)f2b(src[3]) << 16);
    *(uint2*)((char*)ws + 311296 + E * 512 + lane * 8) = make_uint2(lo, hi);
  }
}

__global__ __launch_bounds__(1024) void prithvi_fused(
    const float* __restrict__ x,     const float* __restrict__ conv_w,
    const float* __restrict__ bn_g,  const float* __restrict__ bn_b,
    const float* __restrict__ bn_m,  const float* __restrict__ bn_v,
    const float* __restrict__ w_in,  const float* __restrict__ qkv_b,
    const float* __restrict__ ob,    const float* __restrict__ ln1_g,
    const float* __restrict__ ln1_b, const float* __restrict__ ff1_b,
    const float* __restrict__ ff2_b, const float* __restrict__ ln2_g,
    const float* __restrict__ ln2_b, const float* __restrict__ w_out,
    const float* __restrict__ b_out, const float* __restrict__ ws,
    float* __restrict__ out)
{
  // g2 24576 | HB slots 16x2432=38912 (conv stg 12288 aliases) | peL 4352
  __shared__ __align__(16) char smem[67840];
  unsigned short* g2 = (unsigned short*)smem;   // [256 sl][12 t][4 c] bf16
  char* twb = smem + 24576;
  float* peL = (float*)(smem + 63488);           // [16 t][stride 68] fp32

  const int sp = blockIdx.x;
  const int tid = threadIdx.x, lane = tid & 63, wave = tid >> 6;

  // ---- pe table ----
  {
    int t_ = tid >> 6, d_ = tid & 63;
    float freq = expf(-(float)(d_ & ~1) * (9.210340371976184f / 64.f));
    float a = freq * (float)t_;
    peL[t_ * 68 + d_] = (d_ & 1) ? cosf(a) : sinf(a);
  }

  // ---------------- conv: 1 oc/thread, x staged 4 passes ----
  {
    float* stg = (float*)twb;   // 12288B
    float acc[12];
#pragma unroll
    for (int t = 0; t < 12; ++t) acc[t] = 0.f;
    const int c_ = tid >> 8, jj = tid & 255;
    const int oc = c_ * 256 + jj;
    const float* wrow = conv_w + (size_t)oc * 1024;
#pragma unroll 1
    for (int p = 0; p < 4; ++p) {
      for (int ch2 = tid; ch2 < 3072; ch2 += 1024) {
        int e = ch2 / 12, t = ch2 - 12 * e;
        stg[t * 256 + e] = x[(size_t)((p * 256 + e) * 12 + t) * 256 + sp];
      }
      __syncthreads();
      for (int eb = 0; eb < 256; eb += 4) {
        float4 w4 = *(const float4*)(wrow + p * 256 + eb);
#pragma unroll
        for (int t = 0; t < 12; ++t) {
          float4 xv = *(const float4*)&stg[t * 256 + eb];
          acc[t] = fmaf(xv.x, w4.x, acc[t]);
          acc[t] = fmaf(xv.y, w4.y, acc[t]);
          acc[t] = fmaf(xv.z, w4.z, acc[t]);
          acc[t] = fmaf(xv.w, w4.w, acc[t]);
        }
      }
      __syncthreads();
    }
    float sc = bn_g[oc] * rsqrtf(bn_v[oc] + 1e-5f);
    float sh = fmaf(-bn_m[oc], sc, bn_b[oc]);
#pragma unroll
    for (int t = 0; t < 12; ++t) {
      float z = fmaf(acc[t], sc, sh);
      g2[jj * 48 + t * 4 + c_] = f2b(0.5f * z * (1.f + erff(z * 0.70710678118654752f)));
    }
  }
  __syncthreads();   // g2 + peL read-only; twb free for HB slots

  // ---------------- phase 3: 1 seq at a time, 16 waves, 16 seqs/wave ----
  const int ln = lane & 15, grp = lane >> 4;
  char* HB = twb + wave * 2432;
  const u4v* WS = (const u4v*)ws;
#define BT(T) __builtin_bit_cast(s8v, WS[(T) * 64 + lane])
#define BT2(T2) BT(240 + (T2))
#define WO16(E) __builtin_bit_cast(s4v, *(const uint2*)((const char*)ws + 229376 + (E) * 512 + lane * 8))
#define W2T(E2) WO16(160 + (E2))
#define STROW(BUF, ROW, COL, VAL) \
  ((unsigned short*)(BUF))[(ROW) * 76 + (COL)] = (VAL)

  const float bo0 = b_out[0];

#pragma unroll 1
  for (int itr = 0; itr < 16; ++itr) {
    const int sl = wave * 16 + itr;   // seq 0..255
    f4v v[4];

    // ---- h0 (fp32 C-frag) -> HB bf16 ----
    {
      int tb = (grp < 3) ? grp * 4 : 0;
#pragma unroll
      for (int i = 0; i < 4; ++i) {
        uint2 gu = *(const uint2*)(g2 + sl * 48 + (tb + i) * 4);
        float g0 = b2f((unsigned short)(gu.x & 0xffff));
        float g1 = b2f((unsigned short)(gu.x >> 16));
        float g2v = b2f((unsigned short)(gu.y & 0xffff));
        float g3 = b2f((unsigned short)(gu.y >> 16));
#pragma unroll
        for (int j = 0; j < 4; ++j) {
          float4 wi = *(const float4*)(w_in + (j * 16 + ln) * 4);
          float peij = peL[(grp * 4 + i) * 68 + j * 16 + ln];
          v[j][i] = fmaf(g0, wi.x, fmaf(g1, wi.y,
                    fmaf(g2v, wi.z, fmaf(g3, wi.w, peij))));
        }
      }
#pragma unroll
      for (int i = 0; i < 4; ++i)
#pragma unroll
        for (int j = 0; j < 4; ++j)
          STROW(HB, grp * 4 + i, j * 16 + ln, f2b(v[j][i]));
    }

#pragma unroll 1
    for (int l = 0; l < 2; ++l) {
      const f4v z4 = {0.f, 0.f, 0.f, 0.f};
      s4v Ot[4];
      // ---- fused per-head QKV + attention, all registers ----
      {
        s8v a0 = *(const s8v*)(HB + ln * 152 + grp * 16);
        s8v a1 = *(const s8v*)(HB + ln * 152 + 64 + grp * 16);
#pragma unroll
        for (int hh = 0; hh < 4; ++hh) {
          float4 bq = *(const float4*)(qkv_b + l * 192 + hh * 16 + grp * 4);
          f4v cq = {bq.x, bq.y, bq.z, bq.w};
          cq = MFMA32(BT(192 + l * 16 + hh * 2 + 0), a0, cq);
          cq = MFMA32(BT(192 + l * 16 + hh * 2 + 1), a1, cq);
          float4 bk = *(const float4*)(qkv_b + l * 192 + 64 + hh * 16 + grp * 4);
          f4v ck = {bk.x, bk.y, bk.z, bk.w};
          ck = MFMA32(BT(192 + l * 16 + 8 + hh * 2 + 0), a0, ck);
          ck = MFMA32(BT(192 + l * 16 + 8 + hh * 2 + 1), a1, ck);
          float bb = qkv_b[l * 192 + 128 + hh * 16 + ln];
          f4v cv = {bb, bb, bb, bb};
          cv = MFMA32(a0, BT(l * 24 + 8 + hh), cv);
          cv = MFMA32(a1, BT(l * 24 + 20 + hh), cv);
          s4v q4 = c4(cq), k4 = c4(ck), v4 = c4(cv);
          f4v sc = MFMA16(k4, q4, z4);   // lane: score(q=ln, k=grp*4+i)
          float e0, e1, e2, e3;
          if (grp == 3) { e0 = e1 = e2 = e3 = 0.f; }
          else {
            e0 = __expf(sc[0] * 0.25f); e1 = __expf(sc[1] * 0.25f);
            e2 = __expf(sc[2] * 0.25f); e3 = __expf(sc[3] * 0.25f);
          }
          float sm = (e0 + e1) + (e2 + e3);
          sm += __shfl_xor(sm, 16);
          sm += __shfl_xor(sm, 32);
          float inv = __builtin_amdgcn_rcpf(sm);
          s4v aP;
          aP[0] = (short)f2b(e0 * inv); aP[1] = (short)f2b(e1 * inv);
          aP[2] = (short)f2b(e2 * inv); aP[3] = (short)f2b(e3 * inv);
          Ot[hh] = c4(MFMA16(v4, aP, z4));
        }
      }
      // ---- O-proj ----
      {
#pragma unroll
        for (int jo = 0; jo < 4; ++jo) {
          float bb = ob[l * 64 + jo * 16 + ln];
          f4v bb4 = {bb, bb, bb, bb};
          v[jo] += bb4;
        }
#pragma unroll
        for (int hh = 0; hh < 4; ++hh)
#pragma unroll
          for (int jo = 0; jo < 4; ++jo)
            v[jo] = MFMA16(Ot[hh], WO16(l * 16 + hh * 4 + jo), v[jo]);
      }
      // ---- LN1 -> HB ----
      {
        const float* gp = ln1_g + l * 64;
        const float* bp = ln1_b + l * 64;
#pragma unroll
        for (int i = 0; i < 4; ++i) {
          float sm = v[0][i] + v[1][i] + v[2][i] + v[3][i];
          sm += __shfl_xor(sm, 1); sm += __shfl_xor(sm, 2);
          sm += __shfl_xor(sm, 4); sm += __shfl_xor(sm, 8);
          float mean = sm * 0.015625f;
          float q = 0.f;
#pragma unroll
          for (int j = 0; j < 4; ++j) { float d = v[j][i] - mean; q = fmaf(d, d, q); }
          q += __shfl_xor(q, 1); q += __shfl_xor(q, 2);
          q += __shfl_xor(q, 4); q += __shfl_xor(q, 8);
          float rs = rsqrtf(q * 0.015625f + 1e-5f);
#pragma unroll
          for (int j = 0; j < 4; ++j) {
            float nv = fmaf((v[j][i] - mean) * rs, gp[j * 16 + ln], bp[j * 16 + ln]);
            v[j][i] = nv;
            STROW(HB, grp * 4 + i, j * 16 + ln, f2b(nv));
          }
        }
      }
      // ---- FF: register-resident (F^T tiles; F^T-frag-as-A == F) ----
      {
        s8v ha0 = *(const s8v*)(HB + ln * 152 + grp * 16);
        s8v ha1 = *(const s8v*)(HB + ln * 152 + 64 + grp * 16);
#pragma unroll
        for (int jo = 0; jo < 4; ++jo) {
          float bb = ff2_b[l * 64 + jo * 16 + ln];
          f4v bb4 = {bb, bb, bb, bb};
          v[jo] += bb4;
        }
#pragma unroll
        for (int ft = 0; ft < 16; ++ft) {
          float4 b4 = *(const float4*)(ff1_b + l * 256 + ft * 16 + grp * 4);
          f4v c = {b4.x, b4.y, b4.z, b4.w};
          c = MFMA32(BT2(l * 32 + ft * 2 + 0), ha0, c);
          c = MFMA32(BT2(l * 32 + ft * 2 + 1), ha1, c);
#pragma unroll
          for (int i = 0; i < 4; ++i) c[i] = fmaxf(c[i], 0.f);
          s4v fv = c4(c);
          v[0] = MFMA16(fv, W2T(l * 64 + ft * 4 + 0), v[0]);
          v[1] = MFMA16(fv, W2T(l * 64 + ft * 4 + 1), v[1]);
          v[2] = MFMA16(fv, W2T(l * 64 + ft * 4 + 2), v[2]);
          v[3] = MFMA16(fv, W2T(l * 64 + ft * 4 + 3), v[3]);
        }
      }
      // ---- LN2 (store HB only if another layer follows) ----
      {
        const float* gp = ln2_g + l * 64;
        const float* bp = ln2_b + l * 64;
#pragma unroll
        for (int i = 0; i < 4; ++i) {
          float sm = v[0][i] + v[1][i] + v[2][i] + v[3][i];
          sm += __shfl_xor(sm, 1); sm += __shfl_xor(sm, 2);
          sm += __shfl_xor(sm, 4); sm += __shfl_xor(sm, 8);
          float mean = sm * 0.015625f;
          float q = 0.f;
#pragma unroll
          for (int j = 0; j < 4; ++j) { float d = v[j][i] - mean; q = fmaf(d, d, q); }
          q += __shfl_xor(q, 1); q += __shfl_xor(q, 2);
          q += __shfl_xor(q, 4); q += __shfl_xor(q, 8);
          float rs = rsqrtf(q * 0.015625f + 1e-5f);
#pragma unroll
          for (int j = 0; j < 4; ++j) {
            float nv = fmaf((v[j][i] - mean) * rs, gp[j * 16 + ln], bp[j * 16 + ln]);
            v[j][i] = nv;
            if (l == 0) STROW(HB, grp * 4 + i, j * 16 + ln, f2b(nv));
          }
        }
      }
    } // layer

    // ---- head ----
    {
      float dp = 0.f;
#pragma unroll
      for (int j = 0; j < 4; ++j) {
        float c0 = (grp < 3) ? (v[j][0] + v[j][1] + v[j][2] + v[j][3]) : 0.f;
        c0 += __shfl_xor(c0, 16);
        c0 += __shfl_xor(c0, 32);
        dp = fmaf(c0, w_out[j * 16 + ln], dp);
      }
      dp += __shfl_xor(dp, 1);
      dp += __shfl_xor(dp, 2);
      dp += __shfl_xor(dp, 4);
      dp += __shfl_xor(dp, 8);
      if (lane == 0) {
        float logit = dp * (1.f / 12.f) + bo0;
        int hf = ((sp >> 4) << 4) | (sl >> 4);
        int wf = ((sp & 15) << 4) | (sl & 15);
        out[hf * 256 + wf] = 1.f / (1.f + expf(-logit));
      }
    }
  } // seq loop
#undef BT
#undef BT2
#undef WO16
#undef W2T
#undef STROW
}

extern "C" void kernel_launch(void* const* d_in, const int* in_sizes, int n_in,
                              void* d_out, int out_size, void* d_ws, size_t ws_size,
                              hipStream_t stream) {
  (void)in_sizes; (void)n_in; (void)out_size; (void)ws_size;
  wpack<<<112, 256, 0, stream>>>(
      (const float*)d_in[7],  (const float*)d_in[9],
      (const float*)d_in[13], (const float*)d_in[15], (unsigned int*)d_ws);
  prithvi_fused<<<256, 1024, 0, stream>>>(
      (const float*)d_in[0],  (const float*)d_in[1],  (const float*)d_in[2],
      (const float*)d_in[3],  (const float*)d_in[4],  (const float*)d_in[5],
      (const float*)d_in[6],  (const float*)d_in[8],  (const float*)d_in[10],
      (const float*)d_in[11], (const float*)d_in[12], (const float*)d_in[14],
      (const float*)d_in[16], (const float*)d_in[17], (const float*)d_in[18],
      (const float*)d_in[19], (const float*)d_in[20], (const float*)d_ws,
      (float*)d_out);
}

// Round 21
// 737.663 us; speedup vs baseline: 1.4461x; 1.2290x over previous
//
#include <hip/hip_runtime.h>
#include <math.h>

// R20 = R16 (749us best) + parallel-chain LayerNorm: var = E[x^2] - mean^2,
// so the sum and sumsq shfl reductions are independent chains (serial depth
// 8 -> 4 cross-lane hops per LN) and 16 subs/LN vanish. Everything else
// identical to R16: register attention (A-pack Q/K, C-frag algebra), LDS-FF,
// 256 blocks x 1024 thr, 16 waves/CU.

typedef __attribute__((ext_vector_type(8))) short s8v;
typedef __attribute__((ext_vector_type(4))) short s4v;
typedef __attribute__((ext_vector_type(4))) float f4v;
typedef __attribute__((ext_vector_type(4))) unsigned int u4v;

#define MFMA32(A, B, C) __builtin_amdgcn_mfma_f32_16x16x32_bf16((A), (B), (C), 0, 0, 0)
#define MFMA16(A, B, C) __builtin_amdgcn_mfma_f32_16x16x16bf16_1k((A), (B), (C), 0, 0, 0)

static __device__ __forceinline__ unsigned short f2b(float f) {
  return __builtin_bit_cast(unsigned short, (__bf16)f);
}
static __device__ __forceinline__ float b2f(unsigned short h) {
  return __builtin_bit_cast(float, ((unsigned)h) << 16);
}
static __device__ __forceinline__ s4v c4(f4v v) {
  s4v r;
  r[0] = (short)f2b(v[0]); r[1] = (short)f2b(v[1]);
  r[2] = (short)f2b(v[2]); r[3] = (short)f2b(v[3]);
  return r;
}

// ---- prologue: pack weights (bf16) ----
// B-pack tiles (MFMA32 B-op), 1024B each, T=0..191: lane holds
//   B[k=kk*32+(l>>4)*8+e][n=j*16+(l&15)], e=0..7
//   qkv T=l*24+kk*12+j | ow 48+l*8+kk*4+j | ff1 64+l*32+kk*16+j | ff2 128+l*32+kkg*4+j
// A-pack tiles (MFMA32 A-op) T=192..223: lane holds W[m=jo*16+(l&15)][k=kk*32+(l>>4)*8+e]
//   T = 192 + l*16 + mat*8 + jo*2 + kk  (mat 0=Q,1=K)
// WoT16 packs (MFMA16 B-op), 512B each at byte 229376: E = l*16 + hh*4 + jo:
//   lane holds Wo[jo*16+(l&15)][hh*16+(l>>4)*4+e], e=0..3
__global__ __launch_bounds__(256) void wpack(
    const float* __restrict__ qkv_w, const float* __restrict__ ow,
    const float* __restrict__ ff1_w, const float* __restrict__ ff2_w,
    unsigned int* __restrict__ ws) {
  int gid = blockIdx.x * 256 + threadIdx.x;   // 0..16383
  int tIdx = gid >> 6, lane = gid & 63;
  int ln = lane & 15, grp = lane >> 4;
  if (tIdx < 224) {
    const float* src;
    if (tIdx < 48) {
      int l = tIdx / 24, r = tIdx % 24, kk = r / 12, j = r % 12;
      src = qkv_w + l * 12288 + (j * 16 + ln) * 64 + kk * 32 + grp * 8;
    } else if (tIdx < 64) {
      int u = tIdx - 48, l = u / 8, r = u % 8, kk = r / 4, j = r % 4;
      src = ow + l * 4096 + (j * 16 + ln) * 64 + kk * 32 + grp * 8;
    } else if (tIdx < 128) {
      int u = tIdx - 64, l = u / 32, r = u % 32, kk = r / 16, j = r % 16;
      src = ff1_w + l * 16384 + (j * 16 + ln) * 64 + kk * 32 + grp * 8;
    } else if (tIdx < 192) {
      int u = tIdx - 128, l = u / 32, r = u % 32, kk = r / 4, j = r % 4;
      src = ff2_w + l * 16384 + (j * 16 + ln) * 256 + kk * 32 + grp * 8;
    } else {
      int u = tIdx - 192, l = u / 16, r = u % 16, mat = r / 8, q = r % 8, jo = q / 2, kk = q % 2;
      src = qkv_w + l * 12288 + mat * 4096 + (jo * 16 + ln) * 64 + kk * 32 + grp * 8;
    }
    unsigned p[4];
#pragma unroll
    for (int e = 0; e < 4; ++e)
      p[e] = (unsigned)f2b(src[2 * e]) | ((unsigned)f2b(src[2 * e + 1]) << 16);
    u4v val = {p[0], p[1], p[2], p[3]};
    *(u4v*)(ws + (size_t)gid * 4) = val;
  } else if (tIdx < 256) {
    int E = tIdx - 224, l = E / 16, r = E % 16, hh = r / 4, jo = r % 4;
    const float* src = ow + l * 4096 + (jo * 16 + ln) * 64 + hh * 16 + grp * 4;
    unsigned lo = (unsigned)f2b(src[0]) | ((unsigned)f2b(src[1]) << 16);
    unsigned hi = (unsigned)f2b(src[2]) | ((unsigned)f2b(src[3]) << 16);
    *(uint2*)((char*)ws + 229376 + E * 512 + lane * 8) = make_uint2(lo, hi);
  }
}

__global__ __launch_bounds__(1024) void prithvi_fused(
    const float* __restrict__ x,     const float* __restrict__ conv_w,
    const float* __restrict__ bn_g,  const float* __restrict__ bn_b,
    const float* __restrict__ bn_m,  const float* __restrict__ bn_v,
    const float* __restrict__ w_in,  const float* __restrict__ qkv_b,
    const float* __restrict__ ob,    const float* __restrict__ ln1_g,
    const float* __restrict__ ln1_b, const float* __restrict__ ff1_b,
    const float* __restrict__ ff2_b, const float* __restrict__ ln2_g,
    const float* __restrict__ ln2_b, const float* __restrict__ w_out,
    const float* __restrict__ b_out, const float* __restrict__ ws,
    float* __restrict__ out)
{
  // 24576B g2 + 16 x 6912B slots (HB 2432 | F 4480) + 4352B peL
  __shared__ __align__(16) char smem[139520];
  unsigned short* g2 = (unsigned short*)smem;   // [256 sl][12 t][4 c] bf16
  char* twb = smem + 24576;
  float* peL = (float*)(smem + 135168);          // [16 t][stride 68] fp32

  const int sp = blockIdx.x;
  const int tid = threadIdx.x, lane = tid & 63, wave = tid >> 6;

  // ---- pe table: one element per thread (t = tid>>6, d = tid&63) ----
  {
    int t_ = tid >> 6, d_ = tid & 63;
    float freq = expf(-(float)(d_ & ~1) * (9.210340371976184f / 64.f));
    float a = freq * (float)t_;
    peL[t_ * 68 + d_] = (d_ & 1) ? cosf(a) : sinf(a);
  }

  // ---------------- conv: 1 output channel/thread, x staged 4 passes ----
  {
    float* stg = (float*)twb;   // 12288B
    float acc[12];
#pragma unroll
    for (int t = 0; t < 12; ++t) acc[t] = 0.f;
    const int c_ = tid >> 8, jj = tid & 255;
    const int oc = c_ * 256 + jj;
    const float* wrow = conv_w + (size_t)oc * 1024;
#pragma unroll 1
    for (int p = 0; p < 4; ++p) {
      for (int ch2 = tid; ch2 < 3072; ch2 += 1024) {
        int e = ch2 / 12, t = ch2 - 12 * e;
        stg[t * 256 + e] = x[(size_t)((p * 256 + e) * 12 + t) * 256 + sp];
      }
      __syncthreads();
      for (int eb = 0; eb < 256; eb += 4) {
        float4 w4 = *(const float4*)(wrow + p * 256 + eb);
#pragma unroll
        for (int t = 0; t < 12; ++t) {
          float4 xv = *(const float4*)&stg[t * 256 + eb];
          acc[t] = fmaf(xv.x, w4.x, acc[t]);
          acc[t] = fmaf(xv.y, w4.y, acc[t]);
          acc[t] = fmaf(xv.z, w4.z, acc[t]);
          acc[t] = fmaf(xv.w, w4.w, acc[t]);
        }
      }
      __syncthreads();
    }
    float sc = bn_g[oc] * rsqrtf(bn_v[oc] + 1e-5f);
    float sh = fmaf(-bn_m[oc], sc, bn_b[oc]);
#pragma unroll
    for (int t = 0; t < 12; ++t) {
      float z = fmaf(acc[t], sc, sh);
      g2[jj * 48 + t * 4 + c_] = f2b(0.5f * z * (1.f + erff(z * 0.70710678118654752f)));
    }
  }
  __syncthreads();   // g2 + peL read-only; twb free for transformer slots

  // ---------------- phase 3: 1 seq at a time, 16 waves ----------------
  const int ln = lane & 15, grp = lane >> 4;
  char* HB = twb + wave * 6912;
  char* FB = HB + 2432;                 // [16 rows][140 ush]
  const u4v* WS = (const u4v*)ws;
#define BT(T) __builtin_bit_cast(s8v, WS[(T) * 64 + lane])
#define WO16(E) __builtin_bit_cast(s4v, *(const uint2*)((const char*)ws + 229376 + (E) * 512 + lane * 8))
#define STROW(BUF, ROW, COL, VAL) \
  ((unsigned short*)(BUF))[(ROW) * 76 + (COL)] = (VAL)

  const float bo0 = b_out[0];

#pragma unroll 1
  for (int itr = 0; itr < 16; ++itr) {
    const int sl = wave * 16 + itr;   // seq 0..255
    f4v v[4];

    // ---- h0 (fp32 C-frag) -> HB bf16 ----
    {
      int tb = (grp < 3) ? grp * 4 : 0;
#pragma unroll
      for (int i = 0; i < 4; ++i) {
        uint2 gu = *(const uint2*)(g2 + sl * 48 + (tb + i) * 4);
        float g0 = b2f((unsigned short)(gu.x & 0xffff));
        float g1 = b2f((unsigned short)(gu.x >> 16));
        float g2v = b2f((unsigned short)(gu.y & 0xffff));
        float g3 = b2f((unsigned short)(gu.y >> 16));
#pragma unroll
        for (int j = 0; j < 4; ++j) {
          float4 wi = *(const float4*)(w_in + (j * 16 + ln) * 4);
          float peij = peL[(grp * 4 + i) * 68 + j * 16 + ln];
          v[j][i] = fmaf(g0, wi.x, fmaf(g1, wi.y,
                    fmaf(g2v, wi.z, fmaf(g3, wi.w, peij))));
        }
      }
#pragma unroll
      for (int i = 0; i < 4; ++i)
#pragma unroll
        for (int j = 0; j < 4; ++j)
          STROW(HB, grp * 4 + i, j * 16 + ln, f2b(v[j][i]));
    }

#pragma unroll 1
    for (int l = 0; l < 2; ++l) {
      const f4v z4 = {0.f, 0.f, 0.f, 0.f};
      s4v Ot[4];
      // ---- fused per-head QKV + attention, all in registers ----
      {
        s8v a0 = *(const s8v*)(HB + ln * 152 + grp * 16);
        s8v a1 = *(const s8v*)(HB + ln * 152 + 64 + grp * 16);
#pragma unroll
        for (int hh = 0; hh < 4; ++hh) {
          // Q^T, K^T: A = weight A-pack, B = h-frag (same register as A use)
          float4 bq = *(const float4*)(qkv_b + l * 192 + hh * 16 + grp * 4);
          f4v cq = {bq.x, bq.y, bq.z, bq.w};
          cq = MFMA32(BT(192 + l * 16 + hh * 2 + 0), a0, cq);
          cq = MFMA32(BT(192 + l * 16 + hh * 2 + 1), a1, cq);
          float4 bk = *(const float4*)(qkv_b + l * 192 + 64 + hh * 16 + grp * 4);
          f4v ck = {bk.x, bk.y, bk.z, bk.w};
          ck = MFMA32(BT(192 + l * 16 + 8 + hh * 2 + 0), a0, ck);
          ck = MFMA32(BT(192 + l * 16 + 8 + hh * 2 + 1), a1, ck);
          // V (normal orientation): A = h-frag, B = B-pack
          float bb = qkv_b[l * 192 + 128 + hh * 16 + ln];
          f4v cv = {bb, bb, bb, bb};
          cv = MFMA32(a0, BT(l * 24 + 8 + hh), cv);
          cv = MFMA32(a1, BT(l * 24 + 20 + hh), cv);
          s4v q4 = c4(cq), k4 = c4(ck), v4 = c4(cv);
          // scores: S^T = K . Q^T (A = K^T-frag-as-A, B = Q^T-frag)
          f4v sc = MFMA16(k4, q4, z4);   // lane: score(q=ln, k=grp*4+i)
          float e0, e1, e2, e3;
          if (grp == 3) { e0 = e1 = e2 = e3 = 0.f; }
          else {
            e0 = __expf(sc[0] * 0.25f); e1 = __expf(sc[1] * 0.25f);
            e2 = __expf(sc[2] * 0.25f); e3 = __expf(sc[3] * 0.25f);
          }
          float sm = (e0 + e1) + (e2 + e3);
          sm += __shfl_xor(sm, 16);
          sm += __shfl_xor(sm, 32);
          float inv = __builtin_amdgcn_rcpf(sm);
          s4v aP;
          aP[0] = (short)f2b(e0 * inv); aP[1] = (short)f2b(e1 * inv);
          aP[2] = (short)f2b(e2 * inv); aP[3] = (short)f2b(e3 * inv);
          // O^T = V^T . P^T (A = V-frag-as-A, B = P-frag)
          Ot[hh] = c4(MFMA16(v4, aP, z4));
        }
      }
      // ---- O-proj: v += O . Wo^T via 16 mfma16 (A = O^T-frag-as-A) ----
      {
#pragma unroll
        for (int jo = 0; jo < 4; ++jo) {
          float bb = ob[l * 64 + jo * 16 + ln];
          f4v bb4 = {bb, bb, bb, bb};
          v[jo] += bb4;
        }
#pragma unroll
        for (int hh = 0; hh < 4; ++hh)
#pragma unroll
          for (int jo = 0; jo < 4; ++jo)
            v[jo] = MFMA16(Ot[hh], WO16(l * 16 + hh * 4 + jo), v[jo]);
      }
      // ---- LN1 -> HB (parallel sum/sumsq chains) ----
      {
        const float* gp = ln1_g + l * 64;
        const float* bp = ln1_b + l * 64;
#pragma unroll
        for (int i = 0; i < 4; ++i) {
          float sm = (v[0][i] + v[1][i]) + (v[2][i] + v[3][i]);
          float sq = v[0][i] * v[0][i];
          sq = fmaf(v[1][i], v[1][i], sq);
          sq = fmaf(v[2][i], v[2][i], sq);
          sq = fmaf(v[3][i], v[3][i], sq);
          sm += __shfl_xor(sm, 1); sq += __shfl_xor(sq, 1);
          sm += __shfl_xor(sm, 2); sq += __shfl_xor(sq, 2);
          sm += __shfl_xor(sm, 4); sq += __shfl_xor(sq, 4);
          sm += __shfl_xor(sm, 8); sq += __shfl_xor(sq, 8);
          float mean = sm * 0.015625f;
          float var = fmaf(-mean, mean, sq * 0.015625f);
          float rs = rsqrtf(var + 1e-5f);
#pragma unroll
          for (int j = 0; j < 4; ++j) {
            float nv = fmaf((v[j][i] - mean) * rs, gp[j * 16 + ln], bp[j * 16 + ln]);
            v[j][i] = nv;
            STROW(HB, grp * 4 + i, j * 16 + ln, f2b(nv));
          }
        }
      }
      // ---- FF: 2 halves of 128 ff-dims through FB (stride 140) ----
      {
        s8v ha0 = *(const s8v*)(HB + ln * 152 + grp * 16);
        s8v ha1 = *(const s8v*)(HB + ln * 152 + 64 + grp * 16);
#pragma unroll
        for (int j = 0; j < 4; ++j) {
          float bb = ff2_b[l * 64 + j * 16 + ln];
          f4v bb4 = {bb, bb, bb, bb};
          v[j] += bb4;
        }
#pragma unroll
        for (int fh = 0; fh < 2; ++fh) {
#pragma unroll
          for (int j8 = 0; j8 < 8; ++j8) {
            int jt = fh * 8 + j8;
            float bb = ff1_b[l * 256 + jt * 16 + ln];
            f4v c = {bb, bb, bb, bb};
            c = MFMA32(ha0, BT(64 + l * 32 + jt), c);
            c = MFMA32(ha1, BT(64 + l * 32 + 16 + jt), c);
#pragma unroll
            for (int i = 0; i < 4; ++i)
              ((unsigned short*)FB)[(grp * 4 + i) * 140 + j8 * 16 + ln] =
                  f2b(fmaxf(c[i], 0.f));
          }
#pragma unroll
          for (int kk2 = 0; kk2 < 4; ++kk2) {
            int kkg = fh * 4 + kk2;
            s8v fa = *(const s8v*)(FB + ln * 280 + kk2 * 64 + grp * 16);
            v[0] = MFMA32(fa, BT(128 + l * 32 + kkg * 4 + 0), v[0]);
            v[1] = MFMA32(fa, BT(128 + l * 32 + kkg * 4 + 1), v[1]);
            v[2] = MFMA32(fa, BT(128 + l * 32 + kkg * 4 + 2), v[2]);
            v[3] = MFMA32(fa, BT(128 + l * 32 + kkg * 4 + 3), v[3]);
          }
        }
      }
      // ---- LN2 (parallel chains; store HB only if another layer follows) ----
      {
        const float* gp = ln2_g + l * 64;
        const float* bp = ln2_b + l * 64;
#pragma unroll
        for (int i = 0; i < 4; ++i) {
          float sm = (v[0][i] + v[1][i]) + (v[2][i] + v[3][i]);
          float sq = v[0][i] * v[0][i];
          sq = fmaf(v[1][i], v[1][i], sq);
          sq = fmaf(v[2][i], v[2][i], sq);
          sq = fmaf(v[3][i], v[3][i], sq);
          sm += __shfl_xor(sm, 1); sq += __shfl_xor(sq, 1);
          sm += __shfl_xor(sm, 2); sq += __shfl_xor(sq, 2);
          sm += __shfl_xor(sm, 4); sq += __shfl_xor(sq, 4);
          sm += __shfl_xor(sm, 8); sq += __shfl_xor(sq, 8);
          float mean = sm * 0.015625f;
          float var = fmaf(-mean, mean, sq * 0.015625f);
          float rs = rsqrtf(var + 1e-5f);
#pragma unroll
          for (int j = 0; j < 4; ++j) {
            float nv = fmaf((v[j][i] - mean) * rs, gp[j * 16 + ln], bp[j * 16 + ln]);
            v[j][i] = nv;
            if (l == 0) STROW(HB, grp * 4 + i, j * 16 + ln, f2b(nv));
          }
        }
      }
    } // layer

    // ---- head: mean over t, dot w_out, sigmoid ----
    {
      float dp = 0.f;
#pragma unroll
      for (int j = 0; j < 4; ++j) {
        float c0 = (grp < 3) ? (v[j][0] + v[j][1] + v[j][2] + v[j][3]) : 0.f;
        c0 += __shfl_xor(c0, 16);
        c0 += __shfl_xor(c0, 32);
        dp = fmaf(c0, w_out[j * 16 + ln], dp);
      }
      dp += __shfl_xor(dp, 1);
      dp += __shfl_xor(dp, 2);
      dp += __shfl_xor(dp, 4);
      dp += __shfl_xor(dp, 8);
      if (lane == 0) {
        float logit = dp * (1.f / 12.f) + bo0;
        int hf = ((sp >> 4) << 4) | (sl >> 4);
        int wf = ((sp & 15) << 4) | (sl & 15);
        out[hf * 256 + wf] = 1.f / (1.f + expf(-logit));
      }
    }
  } // seq loop
#undef BT
#undef WO16
#undef STROW
}

extern "C" void kernel_launch(void* const* d_in, const int* in_sizes, int n_in,
                              void* d_out, int out_size, void* d_ws, size_t ws_size,
                              hipStream_t stream) {
  (void)in_sizes; (void)n_in; (void)out_size; (void)ws_size;
  wpack<<<64, 256, 0, stream>>>(
      (const float*)d_in[7],  (const float*)d_in[9],
      (const float*)d_in[13], (const float*)d_in[15], (unsigned int*)d_ws);
  prithvi_fused<<<256, 1024, 0, stream>>>(
      (const float*)d_in[0],  (const float*)d_in[1],  (const float*)d_in[2],
      (const float*)d_in[3],  (const float*)d_in[4],  (const float*)d_in[5],
      (const float*)d_in[6],  (const float*)d_in[8],  (const float*)d_in[10],
      (const float*)d_in[11], (const float*)d_in[12], (const float*)d_in[14],
      (const float*)d_in[16], (const float*)d_in[17], (const float*)d_in[18],
      (const float*)d_in[19], (const float*)d_in[20], (const float*)d_ws,
      (float*)d_out);
}

// Round 22
// 608.283 us; speedup vs baseline: 1.7536x; 1.2127x over previous
//
#include <hip/hip_runtime.h>
#include <math.h>

// R21 = R20 (737us best) + (a) conv on matrix cores: xs^T bf16 in LDS,
// conv_w pre-packed as A-frags (2MB in ws); 128 MFMA32/wave replaces 12288
// scalar FMA/thread (~40us VALU). BN via LDS scale/shift table; g2 stride
// 48->52 ush (breaks 4-way epilogue write conflict). (b) s_setprio(1)
// around QKV/attn/O-proj and FF MFMA clusters (T5; barrier-free waves).

typedef __attribute__((ext_vector_type(8))) short s8v;
typedef __attribute__((ext_vector_type(4))) short s4v;
typedef __attribute__((ext_vector_type(4))) float f4v;
typedef __attribute__((ext_vector_type(4))) unsigned int u4v;

#define MFMA32(A, B, C) __builtin_amdgcn_mfma_f32_16x16x32_bf16((A), (B), (C), 0, 0, 0)
#define MFMA16(A, B, C) __builtin_amdgcn_mfma_f32_16x16x16bf16_1k((A), (B), (C), 0, 0, 0)

static __device__ __forceinline__ unsigned short f2b(float f) {
  return __builtin_bit_cast(unsigned short, (__bf16)f);
}
static __device__ __forceinline__ float b2f(unsigned short h) {
  return __builtin_bit_cast(float, ((unsigned)h) << 16);
}
static __device__ __forceinline__ s4v c4(f4v v) {
  s4v r;
  r[0] = (short)f2b(v[0]); r[1] = (short)f2b(v[1]);
  r[2] = (short)f2b(v[2]); r[3] = (short)f2b(v[3]);
  return r;
}

// ---- prologue: pack weights (bf16) ----
// B-pack 1KB tiles T=0..191 | A-pack (Wq/Wk) T=192..223 | WO16 512B E=0..31
// at 229376 | conv A-pack CA=0..2047 (1KB each) at 245760:
//   CA = rt*32+kk: lane holds conv_w[rt*16+(l&15)][kk*32+(l>>4)*8+e], e=0..7
__global__ __launch_bounds__(256) void wpack(
    const float* __restrict__ qkv_w, const float* __restrict__ ow,
    const float* __restrict__ ff1_w, const float* __restrict__ ff2_w,
    const float* __restrict__ conv_w, unsigned int* __restrict__ ws) {
  int gid = blockIdx.x * 256 + threadIdx.x;   // 576 blocks -> tIdx 0..2303
  int tIdx = gid >> 6, lane = gid & 63;
  int ln = lane & 15, grp = lane >> 4;
  if (tIdx < 224) {
    const float* src;
    if (tIdx < 48) {
      int l = tIdx / 24, r = tIdx % 24, kk = r / 12, j = r % 12;
      src = qkv_w + l * 12288 + (j * 16 + ln) * 64 + kk * 32 + grp * 8;
    } else if (tIdx < 64) {
      int u = tIdx - 48, l = u / 8, r = u % 8, kk = r / 4, j = r % 4;
      src = ow + l * 4096 + (j * 16 + ln) * 64 + kk * 32 + grp * 8;
    } else if (tIdx < 128) {
      int u = tIdx - 64, l = u / 32, r = u % 32, kk = r / 16, j = r % 16;
      src = ff1_w + l * 16384 + (j * 16 + ln) * 64 + kk * 32 + grp * 8;
    } else if (tIdx < 192) {
      int u = tIdx - 128, l = u / 32, r = u % 32, kk = r / 4, j = r % 4;
      src = ff2_w + l * 16384 + (j * 16 + ln) * 256 + kk * 32 + grp * 8;
    } else {
      int u = tIdx - 192, l = u / 16, r = u % 16, mat = r / 8, q = r % 8, jo = q / 2, kk = q % 2;
      src = qkv_w + l * 12288 + mat * 4096 + (jo * 16 + ln) * 64 + kk * 32 + grp * 8;
    }
    unsigned p[4];
#pragma unroll
    for (int e = 0; e < 4; ++e)
      p[e] = (unsigned)f2b(src[2 * e]) | ((unsigned)f2b(src[2 * e + 1]) << 16);
    u4v val = {p[0], p[1], p[2], p[3]};
    *(u4v*)(ws + (size_t)gid * 4) = val;
  } else if (tIdx < 256) {
    int E = tIdx - 224, l = E / 16, r = E % 16, hh = r / 4, jo = r % 4;
    const float* src = ow + l * 4096 + (jo * 16 + ln) * 64 + hh * 16 + grp * 4;
    unsigned lo = (unsigned)f2b(src[0]) | ((unsigned)f2b(src[1]) << 16);
    unsigned hi = (unsigned)f2b(src[2]) | ((unsigned)f2b(src[3]) << 16);
    *(uint2*)((char*)ws + 229376 + E * 512 + lane * 8) = make_uint2(lo, hi);
  } else {
    int ca = tIdx - 256, rt = ca >> 5, kk = ca & 31;
    const float* src = conv_w + (size_t)(rt * 16 + ln) * 1024 + kk * 32 + grp * 8;
    unsigned p[4];
#pragma unroll
    for (int e = 0; e < 4; ++e)
      p[e] = (unsigned)f2b(src[2 * e]) | ((unsigned)f2b(src[2 * e + 1]) << 16);
    *(u4v*)((char*)ws + 245760 + (size_t)ca * 1024 + lane * 16) =
        (u4v){p[0], p[1], p[2], p[3]};
  }
}

__global__ __launch_bounds__(1024) void prithvi_fused(
    const float* __restrict__ x,     const float* __restrict__ bn_g,
    const float* __restrict__ bn_b,  const float* __restrict__ bn_m,
    const float* __restrict__ bn_v,  const float* __restrict__ w_in,
    const float* __restrict__ qkv_b, const float* __restrict__ ob,
    const float* __restrict__ ln1_g, const float* __restrict__ ln1_b,
    const float* __restrict__ ff1_b, const float* __restrict__ ff2_b,
    const float* __restrict__ ln2_g, const float* __restrict__ ln2_b,
    const float* __restrict__ w_out, const float* __restrict__ b_out,
    const float* __restrict__ ws,    float* __restrict__ out)
{
  // g2 [256][52]ush = 26624 | peL 4352 @26624 | twb @30976:
  //   union{ xs_t [16][1032]ush 33024 + bnT 8192 | 16 x 6912B slots 110592 }
  __shared__ __align__(16) char smem[141568];
  unsigned short* g2 = (unsigned short*)smem;
  float* peL = (float*)(smem + 26624);           // [16 t][stride 68] fp32
  char* twb = smem + 30976;

  const int sp = blockIdx.x;
  const int tid = threadIdx.x, lane = tid & 63, wave = tid >> 6;
  const int ln = lane & 15, grp = lane >> 4;

  // ---- pe table ----
  {
    int t_ = tid >> 6, d_ = tid & 63;
    float freq = expf(-(float)(d_ & ~1) * (9.210340371976184f / 64.f));
    float a = freq * (float)t_;
    peL[t_ * 68 + d_] = (d_ & 1) ? cosf(a) : sinf(a);
  }

  // ---------------- conv via MFMA ----------------
  {
    unsigned short* xs_t = (unsigned short*)twb;   // [16][1032] bf16
    float* bnT = (float*)(twb + 33024);            // [1024][2] fp32
    {
      int oc = tid;
      float sc = bn_g[oc] * rsqrtf(bn_v[oc] + 1e-5f);
      bnT[oc * 2] = sc;
      bnT[oc * 2 + 1] = fmaf(-bn_m[oc], sc, bn_b[oc]);
    }
    for (int ch = tid; ch < 12288; ch += 1024) {
      int e = ch / 12, t = ch - 12 * e;
      xs_t[t * 1032 + e] = f2b(x[(size_t)ch * 256 + sp]);
    }
    __syncthreads();
    // wave owns ocs wave*64 .. +63 (4 row-tiles); B-frag shared across tiles
    f4v acc[4];
#pragma unroll
    for (int rt = 0; rt < 4; ++rt) acc[rt] = (f4v){0.f, 0.f, 0.f, 0.f};
    const char* CA = (const char*)ws + 245760;
#pragma unroll 1
    for (int kk = 0; kk < 32; ++kk) {
      s8v bf = *(const s8v*)((const char*)xs_t + ln * 2064 + kk * 64 + grp * 16);
#pragma unroll
      for (int rt = 0; rt < 4; ++rt) {
        int ca = (wave * 4 + rt) * 32 + kk;
        s8v af = __builtin_bit_cast(s8v,
            *(const u4v*)(CA + (size_t)ca * 1024 + lane * 16));
        acc[rt] = MFMA32(af, bf, acc[rt]);
      }
    }
    // epilogue: BN + exact GELU -> g2 (stride 52; cols t=ln<12 only)
#pragma unroll
    for (int rt = 0; rt < 4; ++rt) {
#pragma unroll
      for (int i = 0; i < 4; ++i) {
        int oc = wave * 64 + rt * 16 + grp * 4 + i;
        float z = fmaf(acc[rt][i], bnT[oc * 2], bnT[oc * 2 + 1]);
        float ge = 0.5f * z * (1.f + erff(z * 0.70710678118654752f));
        if (ln < 12) g2[(oc & 255) * 52 + ln * 4 + (oc >> 8)] = f2b(ge);
      }
    }
  }
  __syncthreads();   // g2 + peL read-only; twb free for HB slots

  // ---------------- phase 3: 1 seq at a time, 16 waves ----------------
  char* HB = twb + wave * 6912;
  char* FB = HB + 2432;                 // [16 rows][140 ush]
  const u4v* WS = (const u4v*)ws;
#define BT(T) __builtin_bit_cast(s8v, WS[(T) * 64 + lane])
#define WO16(E) __builtin_bit_cast(s4v, *(const uint2*)((const char*)ws + 229376 + (E) * 512 + lane * 8))
#define STROW(BUF, ROW, COL, VAL) \
  ((unsigned short*)(BUF))[(ROW) * 76 + (COL)] = (VAL)

  const float bo0 = b_out[0];

#pragma unroll 1
  for (int itr = 0; itr < 16; ++itr) {
    const int sl = wave * 16 + itr;   // seq 0..255
    f4v v[4];

    // ---- h0 (fp32 C-frag) -> HB bf16 ----
    {
      int tb = (grp < 3) ? grp * 4 : 0;
#pragma unroll
      for (int i = 0; i < 4; ++i) {
        uint2 gu = *(const uint2*)(g2 + sl * 52 + (tb + i) * 4);
        float g0 = b2f((unsigned short)(gu.x & 0xffff));
        float g1 = b2f((unsigned short)(gu.x >> 16));
        float g2v = b2f((unsigned short)(gu.y & 0xffff));
        float g3 = b2f((unsigned short)(gu.y >> 16));
#pragma unroll
        for (int j = 0; j < 4; ++j) {
          float4 wi = *(const float4*)(w_in + (j * 16 + ln) * 4);
          float peij = peL[(grp * 4 + i) * 68 + j * 16 + ln];
          v[j][i] = fmaf(g0, wi.x, fmaf(g1, wi.y,
                    fmaf(g2v, wi.z, fmaf(g3, wi.w, peij))));
        }
      }
#pragma unroll
      for (int i = 0; i < 4; ++i)
#pragma unroll
        for (int j = 0; j < 4; ++j)
          STROW(HB, grp * 4 + i, j * 16 + ln, f2b(v[j][i]));
    }

#pragma unroll 1
    for (int l = 0; l < 2; ++l) {
      const f4v z4 = {0.f, 0.f, 0.f, 0.f};
      s4v Ot[4];
      // ---- fused per-head QKV + attention, all in registers ----
      __builtin_amdgcn_s_setprio(1);
      {
        s8v a0 = *(const s8v*)(HB + ln * 152 + grp * 16);
        s8v a1 = *(const s8v*)(HB + ln * 152 + 64 + grp * 16);
#pragma unroll
        for (int hh = 0; hh < 4; ++hh) {
          float4 bq = *(const float4*)(qkv_b + l * 192 + hh * 16 + grp * 4);
          f4v cq = {bq.x, bq.y, bq.z, bq.w};
          cq = MFMA32(BT(192 + l * 16 + hh * 2 + 0), a0, cq);
          cq = MFMA32(BT(192 + l * 16 + hh * 2 + 1), a1, cq);
          float4 bk = *(const float4*)(qkv_b + l * 192 + 64 + hh * 16 + grp * 4);
          f4v ck = {bk.x, bk.y, bk.z, bk.w};
          ck = MFMA32(BT(192 + l * 16 + 8 + hh * 2 + 0), a0, ck);
          ck = MFMA32(BT(192 + l * 16 + 8 + hh * 2 + 1), a1, ck);
          float bb = qkv_b[l * 192 + 128 + hh * 16 + ln];
          f4v cv = {bb, bb, bb, bb};
          cv = MFMA32(a0, BT(l * 24 + 8 + hh), cv);
          cv = MFMA32(a1, BT(l * 24 + 20 + hh), cv);
          s4v q4 = c4(cq), k4 = c4(ck), v4 = c4(cv);
          f4v sc = MFMA16(k4, q4, z4);   // lane: score(q=ln, k=grp*4+i)
          float e0, e1, e2, e3;
          if (grp == 3) { e0 = e1 = e2 = e3 = 0.f; }
          else {
            e0 = __expf(sc[0] * 0.25f); e1 = __expf(sc[1] * 0.25f);
            e2 = __expf(sc[2] * 0.25f); e3 = __expf(sc[3] * 0.25f);
          }
          float sm = (e0 + e1) + (e2 + e3);
          sm += __shfl_xor(sm, 16);
          sm += __shfl_xor(sm, 32);
          float inv = __builtin_amdgcn_rcpf(sm);
          s4v aP;
          aP[0] = (short)f2b(e0 * inv); aP[1] = (short)f2b(e1 * inv);
          aP[2] = (short)f2b(e2 * inv); aP[3] = (short)f2b(e3 * inv);
          Ot[hh] = c4(MFMA16(v4, aP, z4));
        }
      }
      // ---- O-proj: v += O . Wo^T via 16 mfma16 ----
      {
#pragma unroll
        for (int jo = 0; jo < 4; ++jo) {
          float bb = ob[l * 64 + jo * 16 + ln];
          f4v bb4 = {bb, bb, bb, bb};
          v[jo] += bb4;
        }
#pragma unroll
        for (int hh = 0; hh < 4; ++hh)
#pragma unroll
          for (int jo = 0; jo < 4; ++jo)
            v[jo] = MFMA16(Ot[hh], WO16(l * 16 + hh * 4 + jo), v[jo]);
      }
      __builtin_amdgcn_s_setprio(0);
      // ---- LN1 -> HB (parallel sum/sumsq chains) ----
      {
        const float* gp = ln1_g + l * 64;
        const float* bp = ln1_b + l * 64;
#pragma unroll
        for (int i = 0; i < 4; ++i) {
          float sm = (v[0][i] + v[1][i]) + (v[2][i] + v[3][i]);
          float sq = v[0][i] * v[0][i];
          sq = fmaf(v[1][i], v[1][i], sq);
          sq = fmaf(v[2][i], v[2][i], sq);
          sq = fmaf(v[3][i], v[3][i], sq);
          sm += __shfl_xor(sm, 1); sq += __shfl_xor(sq, 1);
          sm += __shfl_xor(sm, 2); sq += __shfl_xor(sq, 2);
          sm += __shfl_xor(sm, 4); sq += __shfl_xor(sq, 4);
          sm += __shfl_xor(sm, 8); sq += __shfl_xor(sq, 8);
          float mean = sm * 0.015625f;
          float var = fmaf(-mean, mean, sq * 0.015625f);
          float rs = rsqrtf(var + 1e-5f);
#pragma unroll
          for (int j = 0; j < 4; ++j) {
            float nv = fmaf((v[j][i] - mean) * rs, gp[j * 16 + ln], bp[j * 16 + ln]);
            v[j][i] = nv;
            STROW(HB, grp * 4 + i, j * 16 + ln, f2b(nv));
          }
        }
      }
      // ---- FF: 2 halves of 128 ff-dims through FB (stride 140) ----
      __builtin_amdgcn_s_setprio(1);
      {
        s8v ha0 = *(const s8v*)(HB + ln * 152 + grp * 16);
        s8v ha1 = *(const s8v*)(HB + ln * 152 + 64 + grp * 16);
#pragma unroll
        for (int j = 0; j < 4; ++j) {
          float bb = ff2_b[l * 64 + j * 16 + ln];
          f4v bb4 = {bb, bb, bb, bb};
          v[j] += bb4;
        }
#pragma unroll
        for (int fh = 0; fh < 2; ++fh) {
#pragma unroll
          for (int j8 = 0; j8 < 8; ++j8) {
            int jt = fh * 8 + j8;
            float bb = ff1_b[l * 256 + jt * 16 + ln];
            f4v c = {bb, bb, bb, bb};
            c = MFMA32(ha0, BT(64 + l * 32 + jt), c);
            c = MFMA32(ha1, BT(64 + l * 32 + 16 + jt), c);
#pragma unroll
            for (int i = 0; i < 4; ++i)
              ((unsigned short*)FB)[(grp * 4 + i) * 140 + j8 * 16 + ln] =
                  f2b(fmaxf(c[i], 0.f));
          }
#pragma unroll
          for (int kk2 = 0; kk2 < 4; ++kk2) {
            int kkg = fh * 4 + kk2;
            s8v fa = *(const s8v*)(FB + ln * 280 + kk2 * 64 + grp * 16);
            v[0] = MFMA32(fa, BT(128 + l * 32 + kkg * 4 + 0), v[0]);
            v[1] = MFMA32(fa, BT(128 + l * 32 + kkg * 4 + 1), v[1]);
            v[2] = MFMA32(fa, BT(128 + l * 32 + kkg * 4 + 2), v[2]);
            v[3] = MFMA32(fa, BT(128 + l * 32 + kkg * 4 + 3), v[3]);
          }
        }
      }
      __builtin_amdgcn_s_setprio(0);
      // ---- LN2 (parallel chains; store HB only if another layer follows) ----
      {
        const float* gp = ln2_g + l * 64;
        const float* bp = ln2_b + l * 64;
#pragma unroll
        for (int i = 0; i < 4; ++i) {
          float sm = (v[0][i] + v[1][i]) + (v[2][i] + v[3][i]);
          float sq = v[0][i] * v[0][i];
          sq = fmaf(v[1][i], v[1][i], sq);
          sq = fmaf(v[2][i], v[2][i], sq);
          sq = fmaf(v[3][i], v[3][i], sq);
          sm += __shfl_xor(sm, 1); sq += __shfl_xor(sq, 1);
          sm += __shfl_xor(sm, 2); sq += __shfl_xor(sq, 2);
          sm += __shfl_xor(sm, 4); sq += __shfl_xor(sq, 4);
          sm += __shfl_xor(sm, 8); sq += __shfl_xor(sq, 8);
          float mean = sm * 0.015625f;
          float var = fmaf(-mean, mean, sq * 0.015625f);
          float rs = rsqrtf(var + 1e-5f);
#pragma unroll
          for (int j = 0; j < 4; ++j) {
            float nv = fmaf((v[j][i] - mean) * rs, gp[j * 16 + ln], bp[j * 16 + ln]);
            v[j][i] = nv;
            if (l == 0) STROW(HB, grp * 4 + i, j * 16 + ln, f2b(nv));
          }
        }
      }
    } // layer

    // ---- head: mean over t, dot w_out, sigmoid ----
    {
      float dp = 0.f;
#pragma unroll
      for (int j = 0; j < 4; ++j) {
        float c0 = (grp < 3) ? (v[j][0] + v[j][1] + v[j][2] + v[j][3]) : 0.f;
        c0 += __shfl_xor(c0, 16);
        c0 += __shfl_xor(c0, 32);
        dp = fmaf(c0, w_out[j * 16 + ln], dp);
      }
      dp += __shfl_xor(dp, 1);
      dp += __shfl_xor(dp, 2);
      dp += __shfl_xor(dp, 4);
      dp += __shfl_xor(dp, 8);
      if (lane == 0) {
        float logit = dp * (1.f / 12.f) + bo0;
        int hf = ((sp >> 4) << 4) | (sl >> 4);
        int wf = ((sp & 15) << 4) | (sl & 15);
        out[hf * 256 + wf] = 1.f / (1.f + expf(-logit));
      }
    }
  } // seq loop
#undef BT
#undef WO16
#undef STROW
}

extern "C" void kernel_launch(void* const* d_in, const int* in_sizes, int n_in,
                              void* d_out, int out_size, void* d_ws, size_t ws_size,
                              hipStream_t stream) {
  (void)in_sizes; (void)n_in; (void)out_size; (void)ws_size;
  wpack<<<576, 256, 0, stream>>>(
      (const float*)d_in[7],  (const float*)d_in[9],
      (const float*)d_in[13], (const float*)d_in[15],
      (const float*)d_in[1],  (unsigned int*)d_ws);
  prithvi_fused<<<256, 1024, 0, stream>>>(
      (const float*)d_in[0],  (const float*)d_in[2],  (const float*)d_in[3],
      (const float*)d_in[4],  (const float*)d_in[5],  (const float*)d_in[6],
      (const float*)d_in[8],  (const float*)d_in[10], (const float*)d_in[11],
      (const float*)d_in[12], (const float*)d_in[14], (const float*)d_in[16],
      (const float*)d_in[17], (const float*)d_in[18], (const float*)d_in[19],
      (const float*)d_in[20], (const float*)d_ws,
      (float*)d_out);
}

// Round 24
// 500.297 us; speedup vs baseline: 2.1322x; 1.2158x over previous
//
#include <hip/hip_runtime.h>
#include <math.h>

// R23 = R21 (608us) + parameter-load hoisting, fixed layout:
// ptab (f4v[368], 5888B) + ffbT (float[512], 2048B) in LDS, indexed by the
// parameter's true symmetry: grp-f4v for Q/K bias frags (C rows=grp*4+i),
// ln-f4v for V/O/FF2 biases + LN g/b + w_in frags + w_out (C cols=ln),
// flat copy for ff1_b (scalar per (l,jt,ln)). ~40 VMEM/seq-layer -> 0.
// setprio(1) around conv MFMA too. LDS 149760.

typedef __attribute__((ext_vector_type(8))) short s8v;
typedef __attribute__((ext_vector_type(4))) short s4v;
typedef __attribute__((ext_vector_type(4))) float f4v;
typedef __attribute__((ext_vector_type(4))) unsigned int u4v;

#define MFMA32(A, B, C) __builtin_amdgcn_mfma_f32_16x16x32_bf16((A), (B), (C), 0, 0, 0)
#define MFMA16(A, B, C) __builtin_amdgcn_mfma_f32_16x16x16bf16_1k((A), (B), (C), 0, 0, 0)

static __device__ __forceinline__ unsigned short f2b(float f) {
  return __builtin_bit_cast(unsigned short, (__bf16)f);
}
static __device__ __forceinline__ float b2f(unsigned short h) {
  return __builtin_bit_cast(float, ((unsigned)h) << 16);
}
static __device__ __forceinline__ s4v c4(f4v v) {
  s4v r;
  r[0] = (short)f2b(v[0]); r[1] = (short)f2b(v[1]);
  r[2] = (short)f2b(v[2]); r[3] = (short)f2b(v[3]);
  return r;
}

// ---- prologue: pack weights (bf16) ----
// B-pack 1KB tiles T=0..191 | A-pack (Wq/Wk) T=192..223 | WO16 512B E=0..31
// at 229376 | conv A-pack CA=0..2047 (1KB each) at 245760
__global__ __launch_bounds__(256) void wpack(
    const float* __restrict__ qkv_w, const float* __restrict__ ow,
    const float* __restrict__ ff1_w, const float* __restrict__ ff2_w,
    const float* __restrict__ conv_w, unsigned int* __restrict__ ws) {
  int gid = blockIdx.x * 256 + threadIdx.x;   // 576 blocks -> tIdx 0..2303
  int tIdx = gid >> 6, lane = gid & 63;
  int ln = lane & 15, grp = lane >> 4;
  if (tIdx < 224) {
    const float* src;
    if (tIdx < 48) {
      int l = tIdx / 24, r = tIdx % 24, kk = r / 12, j = r % 12;
      src = qkv_w + l * 12288 + (j * 16 + ln) * 64 + kk * 32 + grp * 8;
    } else if (tIdx < 64) {
      int u = tIdx - 48, l = u / 8, r = u % 8, kk = r / 4, j = r % 4;
      src = ow + l * 4096 + (j * 16 + ln) * 64 + kk * 32 + grp * 8;
    } else if (tIdx < 128) {
      int u = tIdx - 64, l = u / 32, r = u % 32, kk = r / 16, j = r % 16;
      src = ff1_w + l * 16384 + (j * 16 + ln) * 64 + kk * 32 + grp * 8;
    } else if (tIdx < 192) {
      int u = tIdx - 128, l = u / 32, r = u % 32, kk = r / 4, j = r % 4;
      src = ff2_w + l * 16384 + (j * 16 + ln) * 256 + kk * 32 + grp * 8;
    } else {
      int u = tIdx - 192, l = u / 16, r = u % 16, mat = r / 8, q = r % 8, jo = q / 2, kk = q % 2;
      src = qkv_w + l * 12288 + mat * 4096 + (jo * 16 + ln) * 64 + kk * 32 + grp * 8;
    }
    unsigned p[4];
#pragma unroll
    for (int e = 0; e < 4; ++e)
      p[e] = (unsigned)f2b(src[2 * e]) | ((unsigned)f2b(src[2 * e + 1]) << 16);
    u4v val = {p[0], p[1], p[2], p[3]};
    *(u4v*)(ws + (size_t)gid * 4) = val;
  } else if (tIdx < 256) {
    int E = tIdx - 224, l = E / 16, r = E % 16, hh = r / 4, jo = r % 4;
    const float* src = ow + l * 4096 + (jo * 16 + ln) * 64 + hh * 16 + grp * 4;
    unsigned lo = (unsigned)f2b(src[0]) | ((unsigned)f2b(src[1]) << 16);
    unsigned hi = (unsigned)f2b(src[2]) | ((unsigned)f2b(src[3]) << 16);
    *(uint2*)((char*)ws + 229376 + E * 512 + lane * 8) = make_uint2(lo, hi);
  } else {
    int ca = tIdx - 256, rt = ca >> 5, kk = ca & 31;
    const float* src = conv_w + (size_t)(rt * 16 + ln) * 1024 + kk * 32 + grp * 8;
    unsigned p[4];
#pragma unroll
    for (int e = 0; e < 4; ++e)
      p[e] = (unsigned)f2b(src[2 * e]) | ((unsigned)f2b(src[2 * e + 1]) << 16);
    *(u4v*)((char*)ws + 245760 + (size_t)ca * 1024 + lane * 16) =
        (u4v){p[0], p[1], p[2], p[3]};
  }
}

__global__ __launch_bounds__(1024) void prithvi_fused(
    const float* __restrict__ x,     const float* __restrict__ bn_g,
    const float* __restrict__ bn_b,  const float* __restrict__ bn_m,
    const float* __restrict__ bn_v,  const float* __restrict__ w_in,
    const float* __restrict__ qkv_b, const float* __restrict__ ob,
    const float* __restrict__ ln1_g, const float* __restrict__ ln1_b,
    const float* __restrict__ ff1_b, const float* __restrict__ ff2_b,
    const float* __restrict__ ln2_g, const float* __restrict__ ln2_b,
    const float* __restrict__ w_out, const float* __restrict__ b_out,
    const float* __restrict__ ws,    float* __restrict__ out)
{
  // 0: g2 [256][52]ush 26624 | 26624: peL [16][68]f32 4352
  // 30976: ptab f4v[368] 5888 | 36864: ffbT f32[512] 2048 (pad to 39168)
  // 39168: twb = union{ xs_t 33024 + bnT 8192 | 16 x 6912 slots 110592 }
  __shared__ __align__(16) char smem[149760];
  unsigned short* g2 = (unsigned short*)smem;
  float* peL  = (float*)(smem + 26624);
  f4v*  ptab  = (f4v*)(smem + 30976);
  float* ffbT = (float*)(smem + 36864);
  char* twb = smem + 39168;

  const int sp = blockIdx.x;
  const int tid = threadIdx.x, lane = tid & 63, wave = tid >> 6;
  const int ln = lane & 15, grp = lane >> 4;

  // ---- pe table ----
  {
    int t_ = tid >> 6, d_ = tid & 63;
    float freq = expf(-(float)(d_ & ~1) * (9.210340371976184f / 64.f));
    float a = freq * (float)t_;
    peL[t_ * 68 + d_] = (d_ & 1) ? cosf(a) : sinf(a);
  }
  // ---- param tables ----
  // ptab slots: [0,32) QB(l,hh,g)=l*16+hh*4+g | [32,64) KB | [64,96) VB(l,n)=64+l*16+n
  // [96,128) OB | [128,160) F2B | [160,288) LN(l,k,n)=160+(l*4+k)*16+n
  // [288,352) WIN(j,n)=288+j*16+n | [352,368) WOUT(n)
  if (tid < 368) {
    int s = tid;
    f4v val;
    if (s < 32) {
      int l = s >> 4, r = s & 15, hh = r >> 2, g = r & 3;
      const float* p = qkv_b + l * 192 + hh * 16 + g * 4;
      val = (f4v){p[0], p[1], p[2], p[3]};
    } else if (s < 64) {
      int u = s - 32, l = u >> 4, r = u & 15, hh = r >> 2, g = r & 3;
      const float* p = qkv_b + l * 192 + 64 + hh * 16 + g * 4;
      val = (f4v){p[0], p[1], p[2], p[3]};
    } else if (s < 96) {
      int u = s - 64, l = u >> 4, n = u & 15;
      const float* p = qkv_b + l * 192 + 128;
      val = (f4v){p[n], p[16 + n], p[32 + n], p[48 + n]};
    } else if (s < 128) {
      int u = s - 96, l = u >> 4, n = u & 15;
      const float* p = ob + l * 64;
      val = (f4v){p[n], p[16 + n], p[32 + n], p[48 + n]};
    } else if (s < 160) {
      int u = s - 128, l = u >> 4, n = u & 15;
      const float* p = ff2_b + l * 64;
      val = (f4v){p[n], p[16 + n], p[32 + n], p[48 + n]};
    } else if (s < 288) {
      int u = s - 160, lk = u >> 4, n = u & 15;
      int l = lk >> 2, kind = lk & 3;
      const float* p = (kind == 0 ? ln1_g : kind == 1 ? ln1_b
                       : kind == 2 ? ln2_g : ln2_b) + l * 64;
      val = (f4v){p[n], p[16 + n], p[32 + n], p[48 + n]};
    } else if (s < 352) {
      int u = s - 288, j = u >> 4, n = u & 15;
      const float* p = w_in + (j * 16 + n) * 4;
      val = (f4v){p[0], p[1], p[2], p[3]};
    } else {
      int n = s - 352;
      val = (f4v){w_out[n], w_out[16 + n], w_out[32 + n], w_out[48 + n]};
    }
    ptab[s] = val;
  }
  if (tid < 512) ffbT[tid] = ff1_b[tid];   // flat [2][256]

  // ---------------- conv via MFMA ----------------
  {
    unsigned short* xs_t = (unsigned short*)twb;   // [16][1032] bf16
    float* bnT = (float*)(twb + 33024);            // [1024][2] fp32
    {
      int oc = tid;
      float sc = bn_g[oc] * rsqrtf(bn_v[oc] + 1e-5f);
      bnT[oc * 2] = sc;
      bnT[oc * 2 + 1] = fmaf(-bn_m[oc], sc, bn_b[oc]);
    }
    for (int ch = tid; ch < 12288; ch += 1024) {
      int e = ch / 12, t = ch - 12 * e;
      xs_t[t * 1032 + e] = f2b(x[(size_t)ch * 256 + sp]);
    }
    __syncthreads();
    f4v acc[4];
#pragma unroll
    for (int rt = 0; rt < 4; ++rt) acc[rt] = (f4v){0.f, 0.f, 0.f, 0.f};
    const char* CA = (const char*)ws + 245760;
    __builtin_amdgcn_s_setprio(1);
#pragma unroll 1
    for (int kk = 0; kk < 32; ++kk) {
      s8v bf = *(const s8v*)((const char*)xs_t + ln * 2064 + kk * 64 + grp * 16);
#pragma unroll
      for (int rt = 0; rt < 4; ++rt) {
        int ca = (wave * 4 + rt) * 32 + kk;
        s8v af = __builtin_bit_cast(s8v,
            *(const u4v*)(CA + (size_t)ca * 1024 + lane * 16));
        acc[rt] = MFMA32(af, bf, acc[rt]);
      }
    }
    __builtin_amdgcn_s_setprio(0);
#pragma unroll
    for (int rt = 0; rt < 4; ++rt) {
#pragma unroll
      for (int i = 0; i < 4; ++i) {
        int oc = wave * 64 + rt * 16 + grp * 4 + i;
        float z = fmaf(acc[rt][i], bnT[oc * 2], bnT[oc * 2 + 1]);
        float ge = 0.5f * z * (1.f + erff(z * 0.70710678118654752f));
        if (ln < 12) g2[(oc & 255) * 52 + ln * 4 + (oc >> 8)] = f2b(ge);
      }
    }
  }
  __syncthreads();   // g2/peL/ptab/ffbT read-only; twb free for HB slots

  // ---------------- phase 3: 1 seq at a time, 16 waves ----------------
  char* HB = twb + wave * 6912;
  char* FB = HB + 2432;                 // [16 rows][140 ush]
  const u4v* WS = (const u4v*)ws;
#define BT(T) __builtin_bit_cast(s8v, WS[(T) * 64 + lane])
#define WO16(E) __builtin_bit_cast(s4v, *(const uint2*)((const char*)ws + 229376 + (E) * 512 + lane * 8))
#define STROW(BUF, ROW, COL, VAL) \
  ((unsigned short*)(BUF))[(ROW) * 76 + (COL)] = (VAL)

  const float bo0 = b_out[0];

#pragma unroll 1
  for (int itr = 0; itr < 16; ++itr) {
    const int sl = wave * 16 + itr;   // seq 0..255
    f4v v[4];

    // ---- h0 (fp32 C-frag) -> HB bf16 ----
    {
      int tb = (grp < 3) ? grp * 4 : 0;
      f4v wi0 = ptab[288 + ln];
      f4v wi1 = ptab[288 + 16 + ln];
      f4v wi2 = ptab[288 + 32 + ln];
      f4v wi3 = ptab[288 + 48 + ln];
#pragma unroll
      for (int i = 0; i < 4; ++i) {
        uint2 gu = *(const uint2*)(g2 + sl * 52 + (tb + i) * 4);
        float g0 = b2f((unsigned short)(gu.x & 0xffff));
        float g1 = b2f((unsigned short)(gu.x >> 16));
        float g2v = b2f((unsigned short)(gu.y & 0xffff));
        float g3 = b2f((unsigned short)(gu.y >> 16));
        float pe0 = peL[(grp * 4 + i) * 68 + ln];
        float pe1 = peL[(grp * 4 + i) * 68 + 16 + ln];
        float pe2 = peL[(grp * 4 + i) * 68 + 32 + ln];
        float pe3 = peL[(grp * 4 + i) * 68 + 48 + ln];
        v[0][i] = fmaf(g0, wi0[0], fmaf(g1, wi0[1], fmaf(g2v, wi0[2], fmaf(g3, wi0[3], pe0))));
        v[1][i] = fmaf(g0, wi1[0], fmaf(g1, wi1[1], fmaf(g2v, wi1[2], fmaf(g3, wi1[3], pe1))));
        v[2][i] = fmaf(g0, wi2[0], fmaf(g1, wi2[1], fmaf(g2v, wi2[2], fmaf(g3, wi2[3], pe2))));
        v[3][i] = fmaf(g0, wi3[0], fmaf(g1, wi3[1], fmaf(g2v, wi3[2], fmaf(g3, wi3[3], pe3))));
      }
#pragma unroll
      for (int i = 0; i < 4; ++i)
#pragma unroll
        for (int j = 0; j < 4; ++j)
          STROW(HB, grp * 4 + i, j * 16 + ln, f2b(v[j][i]));
    }

#pragma unroll 1
    for (int l = 0; l < 2; ++l) {
      const f4v z4 = {0.f, 0.f, 0.f, 0.f};
      s4v Ot[4];
      __builtin_amdgcn_s_setprio(1);
      {
        s8v a0 = *(const s8v*)(HB + ln * 152 + grp * 16);
        s8v a1 = *(const s8v*)(HB + ln * 152 + 64 + grp * 16);
        f4v vb4 = ptab[64 + (l << 4) + ln];
#pragma unroll
        for (int hh = 0; hh < 4; ++hh) {
          f4v cq = ptab[(l << 4) + (hh << 2) + grp];
          cq = MFMA32(BT(192 + l * 16 + hh * 2 + 0), a0, cq);
          cq = MFMA32(BT(192 + l * 16 + hh * 2 + 1), a1, cq);
          f4v ck = ptab[32 + (l << 4) + (hh << 2) + grp];
          ck = MFMA32(BT(192 + l * 16 + 8 + hh * 2 + 0), a0, ck);
          ck = MFMA32(BT(192 + l * 16 + 8 + hh * 2 + 1), a1, ck);
          float bb = vb4[hh];
          f4v cv = {bb, bb, bb, bb};
          cv = MFMA32(a0, BT(l * 24 + 8 + hh), cv);
          cv = MFMA32(a1, BT(l * 24 + 20 + hh), cv);
          s4v q4 = c4(cq), k4 = c4(ck), v4 = c4(cv);
          f4v sc = MFMA16(k4, q4, z4);   // lane: score(q=ln, k=grp*4+i)
          float e0, e1, e2, e3;
          if (grp == 3) { e0 = e1 = e2 = e3 = 0.f; }
          else {
            e0 = __expf(sc[0] * 0.25f); e1 = __expf(sc[1] * 0.25f);
            e2 = __expf(sc[2] * 0.25f); e3 = __expf(sc[3] * 0.25f);
          }
          float sm = (e0 + e1) + (e2 + e3);
          sm += __shfl_xor(sm, 16);
          sm += __shfl_xor(sm, 32);
          float inv = __builtin_amdgcn_rcpf(sm);
          s4v aP;
          aP[0] = (short)f2b(e0 * inv); aP[1] = (short)f2b(e1 * inv);
          aP[2] = (short)f2b(e2 * inv); aP[3] = (short)f2b(e3 * inv);
          Ot[hh] = c4(MFMA16(v4, aP, z4));
        }
      }
      {
        f4v ob4 = ptab[96 + (l << 4) + ln];
#pragma unroll
        for (int jo = 0; jo < 4; ++jo) {
          float bb = ob4[jo];
          f4v bb4 = {bb, bb, bb, bb};
          v[jo] += bb4;
        }
#pragma unroll
        for (int hh = 0; hh < 4; ++hh)
#pragma unroll
          for (int jo = 0; jo < 4; ++jo)
            v[jo] = MFMA16(Ot[hh], WO16(l * 16 + hh * 4 + jo), v[jo]);
      }
      __builtin_amdgcn_s_setprio(0);
      // ---- LN1 -> HB ----
      {
        f4v g4 = ptab[160 + ((l * 4 + 0) << 4) + ln];
        f4v b4 = ptab[160 + ((l * 4 + 1) << 4) + ln];
#pragma unroll
        for (int i = 0; i < 4; ++i) {
          float sm = (v[0][i] + v[1][i]) + (v[2][i] + v[3][i]);
          float sq = v[0][i] * v[0][i];
          sq = fmaf(v[1][i], v[1][i], sq);
          sq = fmaf(v[2][i], v[2][i], sq);
          sq = fmaf(v[3][i], v[3][i], sq);
          sm += __shfl_xor(sm, 1); sq += __shfl_xor(sq, 1);
          sm += __shfl_xor(sm, 2); sq += __shfl_xor(sq, 2);
          sm += __shfl_xor(sm, 4); sq += __shfl_xor(sq, 4);
          sm += __shfl_xor(sm, 8); sq += __shfl_xor(sq, 8);
          float mean = sm * 0.015625f;
          float var = fmaf(-mean, mean, sq * 0.015625f);
          float rs = rsqrtf(var + 1e-5f);
#pragma unroll
          for (int j = 0; j < 4; ++j) {
            float nv = fmaf((v[j][i] - mean) * rs, g4[j], b4[j]);
            v[j][i] = nv;
            STROW(HB, grp * 4 + i, j * 16 + ln, f2b(nv));
          }
        }
      }
      // ---- FF: 2 halves of 128 ff-dims through FB (stride 140) ----
      __builtin_amdgcn_s_setprio(1);
      {
        s8v ha0 = *(const s8v*)(HB + ln * 152 + grp * 16);
        s8v ha1 = *(const s8v*)(HB + ln * 152 + 64 + grp * 16);
        f4v f2b4 = ptab[128 + (l << 4) + ln];
#pragma unroll
        for (int j = 0; j < 4; ++j) {
          float bb = f2b4[j];
          f4v bb4 = {bb, bb, bb, bb};
          v[j] += bb4;
        }
#pragma unroll
        for (int fh = 0; fh < 2; ++fh) {
#pragma unroll
          for (int j8 = 0; j8 < 8; ++j8) {
            int jt = fh * 8 + j8;
            float bb = ffbT[l * 256 + jt * 16 + ln];
            f4v c = {bb, bb, bb, bb};
            c = MFMA32(ha0, BT(64 + l * 32 + jt), c);
            c = MFMA32(ha1, BT(64 + l * 32 + 16 + jt), c);
#pragma unroll
            for (int i = 0; i < 4; ++i)
              ((unsigned short*)FB)[(grp * 4 + i) * 140 + j8 * 16 + ln] =
                  f2b(fmaxf(c[i], 0.f));
          }
#pragma unroll
          for (int kk2 = 0; kk2 < 4; ++kk2) {
            int kkg = fh * 4 + kk2;
            s8v fa = *(const s8v*)(FB + ln * 280 + kk2 * 64 + grp * 16);
            v[0] = MFMA32(fa, BT(128 + l * 32 + kkg * 4 + 0), v[0]);
            v[1] = MFMA32(fa, BT(128 + l * 32 + kkg * 4 + 1), v[1]);
            v[2] = MFMA32(fa, BT(128 + l * 32 + kkg * 4 + 2), v[2]);
            v[3] = MFMA32(fa, BT(128 + l * 32 + kkg * 4 + 3), v[3]);
          }
        }
      }
      __builtin_amdgcn_s_setprio(0);
      // ---- LN2 ----
      {
        f4v g4 = ptab[160 + ((l * 4 + 2) << 4) + ln];
        f4v b4 = ptab[160 + ((l * 4 + 3) << 4) + ln];
#pragma unroll
        for (int i = 0; i < 4; ++i) {
          float sm = (v[0][i] + v[1][i]) + (v[2][i] + v[3][i]);
          float sq = v[0][i] * v[0][i];
          sq = fmaf(v[1][i], v[1][i], sq);
          sq = fmaf(v[2][i], v[2][i], sq);
          sq = fmaf(v[3][i], v[3][i], sq);
          sm += __shfl_xor(sm, 1); sq += __shfl_xor(sq, 1);
          sm += __shfl_xor(sm, 2); sq += __shfl_xor(sq, 2);
          sm += __shfl_xor(sm, 4); sq += __shfl_xor(sq, 4);
          sm += __shfl_xor(sm, 8); sq += __shfl_xor(sq, 8);
          float mean = sm * 0.015625f;
          float var = fmaf(-mean, mean, sq * 0.015625f);
          float rs = rsqrtf(var + 1e-5f);
#pragma unroll
          for (int j = 0; j < 4; ++j) {
            float nv = fmaf((v[j][i] - mean) * rs, g4[j], b4[j]);
            v[j][i] = nv;
            if (l == 0) STROW(HB, grp * 4 + i, j * 16 + ln, f2b(nv));
          }
        }
      }
    } // layer

    // ---- head: mean over t, dot w_out, sigmoid ----
    {
      f4v wo4 = ptab[352 + ln];
      float dp = 0.f;
#pragma unroll
      for (int j = 0; j < 4; ++j) {
        float c0 = (grp < 3) ? (v[j][0] + v[j][1] + v[j][2] + v[j][3]) : 0.f;
        c0 += __shfl_xor(c0, 16);
        c0 += __shfl_xor(c0, 32);
        dp = fmaf(c0, wo4[j], dp);
      }
      dp += __shfl_xor(dp, 1);
      dp += __shfl_xor(dp, 2);
      dp += __shfl_xor(dp, 4);
      dp += __shfl_xor(dp, 8);
      if (lane == 0) {
        float logit = dp * (1.f / 12.f) + bo0;
        int hf = ((sp >> 4) << 4) | (sl >> 4);
        int wf = ((sp & 15) << 4) | (sl & 15);
        out[hf * 256 + wf] = 1.f / (1.f + expf(-logit));
      }
    }
  } // seq loop
#undef BT
#undef WO16
#undef STROW
}

extern "C" void kernel_launch(void* const* d_in, const int* in_sizes, int n_in,
                              void* d_out, int out_size, void* d_ws, size_t ws_size,
                              hipStream_t stream) {
  (void)in_sizes; (void)n_in; (void)out_size; (void)ws_size;
  wpack<<<576, 256, 0, stream>>>(
      (const float*)d_in[7],  (const float*)d_in[9],
      (const float*)d_in[13], (const float*)d_in[15],
      (const float*)d_in[1],  (unsigned int*)d_ws);
  prithvi_fused<<<256, 1024, 0, stream>>>(
      (const float*)d_in[0],  (const float*)d_in[2],  (const float*)d_in[3],
      (const float*)d_in[4],  (const float*)d_in[5],  (const float*)d_in[6],
      (const float*)d_in[8],  (const float*)d_in[10], (const float*)d_in[11],
      (const float*)d_in[12], (const float*)d_in[14], (const float*)d_in[16],
      (const float*)d_in[17], (const float*)d_in[18], (const float*)d_in[19],
      (const float*)d_in[20], (const float*)d_ws,
      (float*)d_out);
}